// Round 8
// baseline (444.299 us; speedup 1.0000x reference)
//
#include <hip/hip_runtime.h>

typedef unsigned short u16;
typedef unsigned int u32;
typedef float f32x4 __attribute__((ext_vector_type(4)));
typedef short bf16x8 __attribute__((ext_vector_type(8)));   // 8 bf16 bit-patterns (4 VGPRs)

#define DEV static __device__ __forceinline__

DEV float bf2f(u16 u){ union{float f; u32 i;} x; x.i = ((u32)u) << 16; return x.f; }
DEV u16 f2bf(float f){ union{float f; u32 i;} x; x.f = f; u32 u = x.i;
  return (u16)((u + 0x7fffu + ((u >> 16) & 1u)) >> 16); }           // RNE
DEV u16 f2h(float f){ _Float16 h = (_Float16)f; u16 u; __builtin_memcpy(&u, &h, 2); return u; }
DEV float h2f(u16 u){ _Float16 h; __builtin_memcpy(&h, &u, 2); return (float)h; }
DEV uint4 pack8(const u16* s){ uint4 v;
  v.x = (u32)s[0] | ((u32)s[1]<<16); v.y = (u32)s[2] | ((u32)s[3]<<16);
  v.z = (u32)s[4] | ((u32)s[5]<<16); v.w = (u32)s[6] | ((u32)s[7]<<16); return v; }
DEV f32x4 mfma16(bf16x8 a, bf16x8 b, f32x4 c){
  return __builtin_amdgcn_mfma_f32_16x16x32_bf16(a, b, c, 0, 0, 0);
}
DEV bf16x8 ldfrag(const u16* p){ return *(const bf16x8*)p; }

constexpr float SCL = 144.269504088896341f;    // 100*log2(e) = 1/(eps*ln2), eps=0.01
constexpr float LOG2MU = -9.99998522680257f;   // log2(1/1024 + 1e-8)

// ---------------- workspace layout ----------------
// Packed activation layout AP[ck][row=b*1024+px][32]: elem = (ck*4096+row)*32+c
constexpr size_t MB = 1ull << 20;
constexpr size_t OFF_G    = 0;                 // f16 [4][1024][1024]
constexpr size_t OFF_GT   = 8*MB;              // f16 transpose
constexpr size_t OFF_U    = 16*MB;             // fp32 [4][1024]
constexpr size_t OFF_V    = OFF_U   + (16<<10);
constexpr size_t OFF_INC  = OFF_V   + (16<<10);// (unused, layout keep)
constexpr size_t OFF_INS  = OFF_INC + (16<<10);
constexpr size_t OFF_CNM  = OFF_INS + (16<<10);
constexpr size_t OFF_CNIS = OFF_CNM + (8<<10);
constexpr size_t OFF_BNS  = OFF_CNIS+ (8<<10);
constexpr size_t OFF_PNP  = OFF_BNS + (4<<10); // pixel-norm partials [2][8][4096] f32 = 256 KB
constexpr size_t OFF_CFH  = 17*MB;             // bf16 [4][1024][512]
constexpr size_t OFF_CFL  = 21*MB;
constexpr size_t OFF_SFH  = 25*MB;
constexpr size_t OFF_SFL  = 29*MB;
constexpr size_t OFF_SNB  = 33*MB;             // bf16 style NCHW [4][512][1024]
constexpr size_t OFF_TN   = 37*MB;             // fp32 t NHWC [4][1024][512]
constexpr size_t OFF_TCP  = 45*MB;             // bf16 packed concat: 32 chunks
constexpr size_t OFF_W1P  = 53*MB;             // frag-order bf16 weights
constexpr size_t OFF_W2P  = OFF_W1P + 9*256*1024*2;
constexpr size_t OFF_W3P  = OFF_W2P + 9*256*256*2;
constexpr size_t OFF_WDP  = OFF_W3P + 9*512*256*2;   // [9][16][512]
constexpr size_t OFF_PIP  = 62*MB;             // bf16 pi packed [4][1024][1024]
// reuse (dead after cgemm/tgemm):
constexpr size_t OFF_Z1  = 17*MB;              // fp32 partials 2x[4096][256]
constexpr size_t OFF_A1P = 25*MB;              // packed bf16, 8 chunks
constexpr size_t OFF_Z2  = 27*MB;              // fp32 partials 2x[4096][256]
constexpr size_t OFF_A2P = 35*MB;              // packed bf16, 8 chunks
constexpr size_t OFF_T2P = 17*MB;              // packed bf16, 16 chunks (z1 dead)

// ---------------- weight pack: coalesced via LDS ----------------
// frag-order: wp[(((g*NCK + ck)*9 + tap)*64 + lane)*8 + e]
//   co = g*16 + (lane&15), ci = ck*32 + ((lane>>4)&3)*8 + e
// Block = one (layer, g, ck): reads 16 rows x 288 contiguous floats, writes 9.2KB contiguous.
__global__ void pack_all_k(const float* __restrict__ w1, const float* __restrict__ w2,
                           const float* __restrict__ w3, const float* __restrict__ wd,
                           u16* __restrict__ w1p, u16* __restrict__ w2p,
                           u16* __restrict__ w3p, u16* __restrict__ wdp){
  int blk = blockIdx.x;
  const float* w; u16* wp; int CI, NCK, rel;
  if (blk < 512){ w = w1; wp = w1p; CI = 1024; NCK = 32; rel = blk; }
  else if (blk < 640){ w = w2; wp = w2p; CI = 256; NCK = 8; rel = blk - 512; }
  else if (blk < 896){ w = w3; wp = w3p; CI = 256; NCK = 8; rel = blk - 640; }
  else {                                        // decoder: small scatter path
    int o = (blk - 896)*256 + threadIdx.x;      // 288 blocks x 256 = 73728
    int ci = o & 511; int r = o >> 9; int co = r & 15; int tap = r >> 4;
    wdp[o] = f2bf((co < 3) ? wd[(size_t)(co*512 + ci)*9 + tap] : 0.f);
    return;
  }
  int g = rel / NCK, ck = rel % NCK;
  __shared__ float L[16*288];                   // [co][ci_local*9+tap], 18.4 KB
  const float* base = w + ((size_t)(g*16)*CI + ck*32)*9;
  #pragma unroll
  for (int i = 0; i < 18; ++i){
    int idx = i*256 + threadIdx.x;              // 0..4607
    int row = idx / 288, col = idx - row*288;
    L[row*288 + col] = base[(size_t)row*CI*9 + col];
  }
  __syncthreads();
  u16* dst = wp + ((size_t)(g*NCK + ck)*9)*512;
  #pragma unroll
  for (int i = 0; i < 18; ++i){
    int j = i*256 + threadIdx.x;                // 0..4607 contiguous dest
    int tap = j >> 9, r = j & 511, lane = r >> 3, e = r & 7;
    int co = lane & 15, cil = ((lane >> 4) & 3)*8 + e;
    dst[j] = f2bf(L[co*288 + cil*9 + tap]);     // stride-9 LDS read: conflict-free
  }
}

// ---------------- fused stats: chan_stats (blocks 0..2047) + pix_part (2048..2303)
__global__ void stats_k(const float* __restrict__ cf, const float* __restrict__ sf,
                        float* __restrict__ cnm, float* __restrict__ cnis,
                        float* __restrict__ part){
  int blk = blockIdx.x;
  if (blk < 2048){                              // content channel stats
    int bd = blk;
    float4 v = ((const float4*)(cf + (size_t)bd*1024))[threadIdx.x];
    float s = v.x+v.y+v.z+v.w;
    float q = v.x*v.x+v.y*v.y+v.z*v.z+v.w*v.w;
    #pragma unroll
    for (int m = 32; m >= 1; m >>= 1){ s += __shfl_xor(s, m, 64); q += __shfl_xor(q, m, 64); }
    __shared__ float ls[4], lq[4];
    int w = threadIdx.x >> 6;
    if ((threadIdx.x & 63) == 0){ ls[w] = s; lq[w] = q; }
    __syncthreads();
    if (threadIdx.x == 0){
      float S = ls[0]+ls[1]+ls[2]+ls[3], Q = lq[0]+lq[1]+lq[2]+lq[3];
      float mean = S * (1.f/1024.f);
      float var  = Q * (1.f/1024.f) - mean*mean;
      cnm[bd] = mean; cnis[bd] = rsqrtf(var + 1e-5f);
    }
    return;
  }
  int rel = blk - 2048;                         // pixel-norm partials
  int x = rel & 15, y = (rel >> 4) & 7, src = rel >> 7;
  const float* in = src ? sf : cf;
  int p = x*256 + threadIdx.x;
  int b = p >> 10, pp = p & 1023;
  const float* base = in + ((size_t)(b*512 + y*64))*1024 + pp;
  float s = 0.f;
  #pragma unroll 8
  for (int d = 0; d < 64; ++d){ float xx = base[(size_t)d*1024]; s += xx*xx; }
  part[((size_t)(src*8 + y))*4096 + p] = s;
}

// NCHW fp32 -> points [p][d] bf16 hi/lo split (+aux); inv-norm computed from partials
__global__ void tsplit_k(const float* __restrict__ src, const float* __restrict__ pnp,
                         u16* __restrict__ hi, u16* __restrict__ lo,
                         u16* __restrict__ aux, int is_style){
  __shared__ float tile[64][65];
  int b = blockIdx.z, p0 = blockIdx.x*64, d0 = blockIdx.y*64;
  int r = threadIdx.x >> 2, c0 = (threadIdx.x & 3) * 16;
  const float* sp = src + ((size_t)(b*512 + d0 + r))*1024 + p0 + c0;
  float v[16];
  #pragma unroll
  for (int e = 0; e < 4; ++e){
    float4 t4 = ((const float4*)sp)[e];
    v[e*4+0]=t4.x; v[e*4+1]=t4.y; v[e*4+2]=t4.z; v[e*4+3]=t4.w;
  }
  #pragma unroll
  for (int j = 0; j < 16; ++j) tile[r][c0+j] = v[j];
  if (is_style){
    u16 t16[16];
    #pragma unroll
    for (int j = 0; j < 16; ++j) t16[j] = f2bf(v[j]);
    uint4* ap = (uint4*)(aux + ((size_t)(b*512 + d0 + r))*1024 + p0 + c0);
    ap[0] = pack8(t16); ap[1] = pack8(t16+8);
  }
  __syncthreads();
  int pr = r, dc0 = c0;
  float inv;
  {
    const float* pp = pnp + (size_t)(is_style ? 8*4096 : 0) + ((b<<10) + p0 + pr);
    float s = 0.f;
    #pragma unroll
    for (int j = 0; j < 8; ++j) s += pp[j*4096];
    inv = rsqrtf(s);
  }
  u16 h16[16], l16[16], t16[16];
  #pragma unroll
  for (int j = 0; j < 16; ++j){
    float x = tile[dc0+j][pr];
    t16[j] = f2bf(x);
    float xn = x * inv;
    u16 h = f2bf(xn);
    h16[j] = h;
    l16[j] = f2bf(xn - bf2f(h));
  }
  size_t orow = (size_t)((b<<10) + p0 + pr);
  uint4* hp = (uint4*)(hi + orow*512 + d0 + dc0);
  uint4* lp = (uint4*)(lo + orow*512 + d0 + dc0);
  hp[0] = pack8(h16); hp[1] = pack8(h16+8);
  lp[0] = pack8(l16); lp[1] = pack8(l16+8);
  if (!is_style){                              // content -> packed tc chunks 16..31
    int D = d0 + dc0;
    size_t off = ((size_t)(16 + (D>>5))*4096 + orow)*32 + (D&31);
    *(uint4*)(aux + off)     = pack8(t16);
    *(uint4*)(aux + off + 8) = pack8(t16+8);
  }
}

// ---------------- C-GEMM: G = (cfn.sfn - 1)*SCL, split bf16; reg-prefetched staging
__global__ __launch_bounds__(256) void cgemm_k(const u16* __restrict__ cfh, const u16* __restrict__ cfl,
        const u16* __restrict__ sfh, const u16* __restrict__ sfl,
        u16* __restrict__ G){
  __shared__ __align__(16) u16 Ah[128*40], Al[128*40], Bh[128*40], Bl[128*40];
  int b = blockIdx.z;
  size_t abase = ((size_t)((b<<10) + blockIdx.x*128))*512;
  size_t bbase = ((size_t)((b<<10) + blockIdx.y*128))*512;
  int lane = threadIdx.x & 63, wid = threadIdx.x >> 6;
  int wm = (wid >> 1)*64, wn = (wid & 1)*64;
  int fr = lane & 15, qd = lane >> 4;
  int sr = threadIdx.x >> 1, sc = (threadIdx.x & 1)*16;
  uint4 p[8];
  auto issue = [&](int kk){
    size_t g0 = (size_t)sr*512 + kk + sc;
    p[0] = *(const uint4*)(cfh + abase + g0); p[1] = *(const uint4*)(cfh + abase + g0 + 8);
    p[2] = *(const uint4*)(cfl + abase + g0); p[3] = *(const uint4*)(cfl + abase + g0 + 8);
    p[4] = *(const uint4*)(sfh + bbase + g0); p[5] = *(const uint4*)(sfh + bbase + g0 + 8);
    p[6] = *(const uint4*)(sfl + bbase + g0); p[7] = *(const uint4*)(sfl + bbase + g0 + 8);
  };
  f32x4 acc[4][4] = {};
  issue(0);
  for (int kk = 0; kk < 512; kk += 32){
    *(uint4*)&Ah[sr*40+sc]   = p[0]; *(uint4*)&Ah[sr*40+sc+8] = p[1];
    *(uint4*)&Al[sr*40+sc]   = p[2]; *(uint4*)&Al[sr*40+sc+8] = p[3];
    *(uint4*)&Bh[sr*40+sc]   = p[4]; *(uint4*)&Bh[sr*40+sc+8] = p[5];
    *(uint4*)&Bl[sr*40+sc]   = p[6]; *(uint4*)&Bl[sr*40+sc+8] = p[7];
    __syncthreads();
    if (kk + 32 < 512) issue(kk + 32);
    bf16x8 bhf[4], blf[4];
    #pragma unroll
    for (int ni = 0; ni < 4; ++ni){
      bhf[ni] = ldfrag(&Bh[(wn + ni*16 + fr)*40 + qd*8]);
      blf[ni] = ldfrag(&Bl[(wn + ni*16 + fr)*40 + qd*8]);
    }
    #pragma unroll
    for (int mi = 0; mi < 4; ++mi){
      bf16x8 ah = ldfrag(&Ah[(wm + mi*16 + fr)*40 + qd*8]);
      bf16x8 al = ldfrag(&Al[(wm + mi*16 + fr)*40 + qd*8]);
      #pragma unroll
      for (int ni = 0; ni < 4; ++ni){
        acc[mi][ni] = mfma16(ah, bhf[ni], acc[mi][ni]);
        acc[mi][ni] = mfma16(ah, blf[ni], acc[mi][ni]);
        acc[mi][ni] = mfma16(al, bhf[ni], acc[mi][ni]);
      }
    }
    __syncthreads();
  }
  size_t gb = ((size_t)b) << 20;
  #pragma unroll
  for (int mi = 0; mi < 4; ++mi)
    #pragma unroll
    for (int ni = 0; ni < 4; ++ni)
      #pragma unroll
      for (int rg = 0; rg < 4; ++rg){
        int ig = blockIdx.x*128 + wm + mi*16 + qd*4 + rg;
        int jg = blockIdx.y*128 + wn + ni*16 + fr;
        G[gb + (size_t)ig*1024 + jg] = f2h((acc[mi][ni][rg] - 1.f) * SCL);
      }
}

// ---------------- f16 64x64 tiled transpose: Gt[b][j][i] = G[b][i][j]
__global__ __launch_bounds__(256) void trans_k(const u16* __restrict__ G, u16* __restrict__ Gt){
  __shared__ u16 T[64][66];
  int b = blockIdx.z, x0 = blockIdx.x*64, y0 = blockIdx.y*64;
  int t = threadIdx.x;
  int r = t >> 2, c0 = (t & 3)*16;
  const u16* src = G + (((size_t)((b<<10) + y0 + r)) << 10) + x0 + c0;
  uint4 v0 = ((const uint4*)src)[0], v1 = ((const uint4*)src)[1];
  u32 w[8] = {v0.x,v0.y,v0.z,v0.w,v1.x,v1.y,v1.z,v1.w};
  #pragma unroll
  for (int k = 0; k < 8; ++k){
    T[r][c0 + 2*k]     = (u16)(w[k] & 0xffffu);
    T[r][c0 + 2*k + 1] = (u16)(w[k] >> 16);
  }
  __syncthreads();
  u16 o[16];
  #pragma unroll
  for (int k = 0; k < 16; ++k) o[k] = T[c0 + k][r];
  u16* dst = Gt + (((size_t)((b<<10) + x0 + r)) << 10) + y0 + c0;
  ((uint4*)dst)[0] = pack8(o);
  ((uint4*)dst)[1] = pack8(o + 8);
}

// ---------------- Sinkhorn log2-domain pass over f16 matrix
__global__ void lse_k(const u16* __restrict__ M, const float* __restrict__ addv,
                      float* __restrict__ outv){
  int row = blockIdx.x*4 + (threadIdx.x >> 6);
  int lane = threadIdx.x & 63;
  int b = row >> 10;
  const uint4* r4 = (const uint4*)(M + ((size_t)row << 10));
  const float4* a4 = (const float4*)(addv + ((size_t)b << 10));
  float x[16]; float mx = -3.0e38f;
  #pragma unroll
  for (int e = 0; e < 2; ++e){
    uint4 g = r4[lane + 64*e];
    float4 a0 = a4[2*(lane + 64*e)];
    float4 a1 = a4[2*(lane + 64*e) + 1];
    u32 w[4] = {g.x, g.y, g.z, g.w};
    float av[8] = {a0.x,a0.y,a0.z,a0.w,a1.x,a1.y,a1.z,a1.w};
    #pragma unroll
    for (int i = 0; i < 8; ++i){
      u16 hv = (u16)((i & 1) ? (w[i>>1] >> 16) : (w[i>>1] & 0xffffu));
      float t = h2f(hv) + av[i];
      x[e*8+i] = t;
      mx = fmaxf(mx, t);
    }
  }
  #pragma unroll
  for (int m = 32; m >= 1; m >>= 1) mx = fmaxf(mx, __shfl_xor(mx, m, 64));
  float s = 0.f;
  #pragma unroll
  for (int i = 0; i < 16; ++i) s += exp2f(x[i] - mx);
  #pragma unroll
  for (int m = 32; m >= 1; m >>= 1) s += __shfl_xor(s, m, 64);
  if (lane == 0) outv[row] = LOG2MU - (mx + log2f(s));
}

// ---------------- pi materialization: pip[row][j] = bf16(2^(G+U+V+10))
__global__ void pi_k(const u16* __restrict__ G, const float* __restrict__ U,
                     const float* __restrict__ V, u16* __restrict__ pip){
  int row = blockIdx.x, b = row >> 10, t = threadIdx.x;
  float ur = U[row] + 10.f;                    // +10: fold pi * 1024
  uint2 g = ((const uint2*)(G + ((size_t)row << 10)))[t];
  float4 vv = ((const float4*)(V + ((size_t)b << 10)))[t];
  u16 o[4];
  o[0] = f2bf(exp2f(h2f((u16)(g.x & 0xffffu)) + vv.x + ur));
  o[1] = f2bf(exp2f(h2f((u16)(g.x >> 16))     + vv.y + ur));
  o[2] = f2bf(exp2f(h2f((u16)(g.y & 0xffffu)) + vv.z + ur));
  o[3] = f2bf(exp2f(h2f((u16)(g.y >> 16))     + vv.w + ur));
  uint2 pk; pk.x = (u32)o[0] | ((u32)o[1]<<16); pk.y = (u32)o[2] | ((u32)o[3]<<16);
  ((uint2*)(pip + ((size_t)row << 10)))[t] = pk;
}

// ---------------- t = pi @ sf: pure bf16 GEMM, 64p x 128d tiles, reg prefetch
__global__ __launch_bounds__(256) void tgemm_k(const u16* __restrict__ pip,
        const u16* __restrict__ snb, float* __restrict__ tn, u16* __restrict__ tcp){
  __shared__ __align__(16) u16 As[64*40], Bs[128*40];
  int b = blockIdx.z, p0 = blockIdx.x*64, d0 = blockIdx.y*128;
  int tid = threadIdx.x, lane = tid & 63, wid = tid >> 6;
  int wm = (wid >> 1)*32, wn = (wid & 1)*64;
  int fr = lane & 15, qd = lane >> 4;
  int a_r = tid >> 2, a_c = (tid & 3)*8;
  int b_r = tid >> 1, b_c = (tid & 1)*16;
  const u16* Arow = pip + (((size_t)((b<<10) + p0 + a_r)) << 10) + a_c;
  const u16* Brow = snb + (((size_t)(b*512 + d0 + b_r)) << 10) + b_c;
  uint4 pa, pb0, pb1;
  auto issue = [&](int kk){
    pa = *(const uint4*)(Arow + kk);
    const uint4* bp = (const uint4*)(Brow + kk);
    pb0 = bp[0]; pb1 = bp[1];
  };
  f32x4 acc[2][4] = {};
  issue(0);
  for (int kk = 0; kk < 1024; kk += 32){
    *(uint4*)&As[a_r*40 + a_c] = pa;
    *(uint4*)&Bs[b_r*40 + b_c] = pb0;
    *(uint4*)&Bs[b_r*40 + b_c + 8] = pb1;
    __syncthreads();
    if (kk + 32 < 1024) issue(kk + 32);
    bf16x8 bfr[4];
    #pragma unroll
    for (int ni = 0; ni < 4; ++ni) bfr[ni] = ldfrag(&Bs[(wn + ni*16 + fr)*40 + qd*8]);
    #pragma unroll
    for (int mi = 0; mi < 2; ++mi){
      bf16x8 afr = ldfrag(&As[(wm + mi*16 + fr)*40 + qd*8]);
      #pragma unroll
      for (int ni = 0; ni < 4; ++ni) acc[mi][ni] = mfma16(afr, bfr[ni], acc[mi][ni]);
    }
    __syncthreads();
  }
  #pragma unroll
  for (int mi = 0; mi < 2; ++mi)
    #pragma unroll
    for (int ni = 0; ni < 4; ++ni)
      #pragma unroll
      for (int rg = 0; rg < 4; ++rg){
        int p = p0 + wm + mi*16 + qd*4 + rg;
        int d = d0 + wn + ni*16 + fr;
        float vout = acc[mi][ni][rg];
        size_t ro = (size_t)((b<<10) + p);
        tn[ro*512 + d] = vout;
        tcp[((size_t)(d>>5)*4096 + ro)*32 + (d&31)] = f2bf(vout);
      }
}

// ---------------- implicit-GEMM 3x3 conv: packed activations, frag-order weights
template<int CI, int CO, int KSPLIT, int MODE>
__global__ __launch_bounds__(256) void conv_k(const u16* __restrict__ inp, const u16* __restrict__ wpk,
        const float* __restrict__ bias, float* __restrict__ fout, u16* __restrict__ bout,
        const u16* __restrict__ tcp, const float* __restrict__ cnm, const float* __restrict__ cnis,
        const float* __restrict__ tn){
  constexpr int NCK_TOT = CI/32, NCK = NCK_TOT/KSPLIT;
  __shared__ __align__(16) u16 As[128*40];
  int b = blockIdx.z & 3, ks = blockIdx.z >> 2;
  int c0 = blockIdx.y*64;
  int r0 = blockIdx.x*2;
  int tid = threadIdx.x, lane = tid & 63, wid = tid >> 6;
  int wm = (wid >> 1)*32, wn = (wid & 1)*32;
  int fr = lane & 15, qd = lane >> 4;
  int ck0 = ks*NCK;
  int hrow = tid >> 1;
  int ah = (tid & 1)*16;
  int gy = r0 - 1 + (hrow >> 5);
  bool a_ok = ((unsigned)gy < 32u);
  size_t arow = (size_t)(b<<10) + (r0-1)*32 + hrow;
  uint4 pa0 = {0,0,0,0}, pa1 = {0,0,0,0};
  auto issueA = [&](int ck){
    if (a_ok){
      const uint4* s = (const uint4*)(inp + ((size_t)(ck0+ck)*4096 + arow)*32 + ah);
      pa0 = s[0]; pa1 = s[1];
    }
  };
  int g0 = (c0 + wn) >> 4;
  const u16* wb0 = wpk + ((size_t)(g0    )*NCK_TOT + ck0)*9*512 + lane*8;
  const u16* wb1 = wpk + ((size_t)(g0 + 1)*NCK_TOT + ck0)*9*512 + lane*8;

  f32x4 acc[2][2] = {};
  issueA(0);
  for (int ck = 0; ck < NCK; ++ck){
    *(uint4*)&As[hrow*40 + ah]     = pa0;
    *(uint4*)&As[hrow*40 + ah + 8] = pa1;
    __syncthreads();
    if (ck + 1 < NCK) issueA(ck + 1);
    #pragma unroll
    for (int tap = 0; tap < 9; ++tap){
      const int dy = tap/3 - 1, dx = tap%3 - 1;
      bf16x8 bf0 = ldfrag(wb0 + (size_t)(ck*9 + tap)*512);
      bf16x8 bf1 = ldfrag(wb1 + (size_t)(ck*9 + tap)*512);
      #pragma unroll
      for (int mi = 0; mi < 2; ++mi){
        int p0w = wm + mi*16;
        int pcol = (p0w & 31) + fr + dx;
        int lr = (p0w >> 5) + dy + 1;
        bool okc = (unsigned)pcol < 32u;
        bf16x8 af = ldfrag(&As[(lr*32 + (okc ? pcol : 0))*40 + qd*8]);
        if (!okc) af = bf16x8(0);
        acc[mi][0] = mfma16(af, bf0, acc[mi][0]);
        acc[mi][1] = mfma16(af, bf1, acc[mi][1]);
      }
    }
    __syncthreads();
  }
  #pragma unroll
  for (int mi = 0; mi < 2; ++mi)
    #pragma unroll
    for (int ni = 0; ni < 2; ++ni)
      #pragma unroll
      for (int rg = 0; rg < 4; ++rg){
        int pp = blockIdx.x*64 + wm + mi*16 + qd*4 + rg;
        int cc = c0 + wn + ni*16 + fr;
        float v = acc[mi][ni][rg];
        size_t ro = (size_t)((b<<10) + pp);
        if (MODE == 0){
          fout[(size_t)ks*4096*CO + ro*CO + cc] = v;
        } else {
          float alpha = v + bias[cc];
          float cn = (bf2f(tcp[((size_t)(16 + (cc>>5))*4096 + ro)*32 + (cc&31)])
                      - cnm[(b<<9) + cc]) * cnis[(b<<9) + cc];
          bout[((size_t)(cc>>5)*4096 + ro)*32 + (cc&31)] = f2bf(alpha*cn + tn[ro*512 + cc]);
        }
      }
}

// ---------------- decoder conv (512 -> 3): VALU reduction over packed t2
__global__ __launch_bounds__(256) void dec_k(const u16* __restrict__ t2p, const u16* __restrict__ wdp,
                                             const float* __restrict__ db, float* __restrict__ out){
  __shared__ float wlds[3*4608];
  int tid = threadIdx.x;
  for (int k = tid; k < 3*4608; k += 256){
    int c = k / 4608, rem = k - c*4608;
    int tap = rem >> 9, ci = rem & 511;
    wlds[k] = bf2f(wdp[(size_t)(tap*16 + c)*512 + ci]);
  }
  __syncthreads();
  int b = blockIdx.x >> 6;
  int p = ((blockIdx.x & 63) << 4) + (tid >> 4);
  int sub = tid & 15;
  int py = p >> 5, px = p & 31;
  float a0 = 0.f, a1 = 0.f, a2 = 0.f;
  for (int tap = 0; tap < 9; ++tap){
    int sy = py + tap/3 - 1, sx = px + tap%3 - 1;
    if (((unsigned)sy < 32u) && ((unsigned)sx < 32u)){
      size_t row = (size_t)((b<<10) + (sy<<5) + sx);
      const float* w0 = wlds + tap*512;
      #pragma unroll
      for (int j = 0; j < 4; ++j){
        int ci0 = j*128 + sub*8;
        uint4 v = *(const uint4*)(t2p + ((size_t)(ci0>>5)*4096 + row)*32 + (ci0&31));
        u32 ww[4] = {v.x, v.y, v.z, v.w};
        #pragma unroll
        for (int e = 0; e < 8; ++e){
          float x = bf2f((u16)((e & 1) ? (ww[e>>1] >> 16) : (ww[e>>1] & 0xffffu)));
          a0 += x * w0[ci0 + e];
          a1 += x * w0[4608 + ci0 + e];
          a2 += x * w0[9216 + ci0 + e];
        }
      }
    }
  }
  #pragma unroll
  for (int m = 8; m >= 1; m >>= 1){
    a0 += __shfl_xor(a0, m, 64);
    a1 += __shfl_xor(a1, m, 64);
    a2 += __shfl_xor(a2, m, 64);
  }
  if (sub == 0){
    out[((size_t)(b*3 + 0) << 10) + p] = a0 + db[0];
    out[((size_t)(b*3 + 1) << 10) + p] = a1 + db[1];
    out[((size_t)(b*3 + 2) << 10) + p] = a2 + db[2];
  }
}

// ---------------- BN over K-split partials: x = relu(za+zb+bias) ----------------
__global__ void bn_stats_k(const float* __restrict__ z, const float* __restrict__ bias,
                           float* __restrict__ sums){
  int c = blockIdx.x*64 + (threadIdx.x & 63);
  int w = threadIdx.x >> 6;
  int rbase = blockIdx.y*512 + w*128;
  float bi = bias[c];
  float s = 0.f, q = 0.f;
  for (int i = 0; i < 128; ++i){
    size_t ro = (size_t)(rbase + i)*256 + c;
    float x = fmaxf(z[ro] + z[4096*256 + ro] + bi, 0.f);
    s += x; q += x*x;
  }
  __shared__ float ls[4][64], lq[4][64];
  ls[w][threadIdx.x & 63] = s; lq[w][threadIdx.x & 63] = q;
  __syncthreads();
  if (threadIdx.x < 64){
    float S = ls[0][threadIdx.x]+ls[1][threadIdx.x]+ls[2][threadIdx.x]+ls[3][threadIdx.x];
    float Q = lq[0][threadIdx.x]+lq[1][threadIdx.x]+lq[2][threadIdx.x]+lq[3][threadIdx.x];
    atomicAdd(&sums[blockIdx.x*64 + threadIdx.x], S);
    atomicAdd(&sums[256 + blockIdx.x*64 + threadIdx.x], Q);
  }
}

// bn_apply with inline finalize
__global__ void bn_apply_k(const float* __restrict__ z, const float* __restrict__ bias,
                           const float* __restrict__ sums, const float* __restrict__ gamma,
                           const float* __restrict__ beta, u16* __restrict__ ap){
  int idx = blockIdx.x*256 + threadIdx.x;
  float4 va = ((const float4*)z)[idx];
  float4 vb = ((const float4*)(z + 4096*256))[idx];
  int row = idx >> 6;
  int cc0 = (idx << 2) & 255;
  float e[4] = {va.x+vb.x, va.y+vb.y, va.z+vb.z, va.w+vb.w};
  u16 o[4];
  #pragma unroll
  for (int k = 0; k < 4; ++k){
    int c = cc0 + k;
    float mean = sums[c] * (1.f/4096.f);
    float var  = sums[256 + c] * (1.f/4096.f) - mean*mean;
    float sc = gamma[c] * rsqrtf(var + 1e-5f);
    float sh = beta[c] - mean*sc;
    float x = fmaxf(e[k] + bias[c], 0.f);
    o[k] = f2bf(x*sc + sh);
  }
  uint2 pk; pk.x = (u32)o[0] | ((u32)o[1]<<16); pk.y = (u32)o[2] | ((u32)o[3]<<16);
  *(uint2*)(ap + ((size_t)(cc0>>5)*4096 + row)*32 + (cc0&31)) = pk;
}

// ---------------- launch ----------------
extern "C" void kernel_launch(void* const* d_in, const int* in_sizes, int n_in,
                              void* d_out, int out_size, void* d_ws, size_t ws_size,
                              hipStream_t stream){
  const float* cf  = (const float*)d_in[0];
  const float* sf  = (const float*)d_in[1];
  const float* w1  = (const float*)d_in[2];
  const float* b1  = (const float*)d_in[3];
  const float* g1  = (const float*)d_in[4];
  const float* be1 = (const float*)d_in[5];
  const float* w2  = (const float*)d_in[6];
  const float* b2  = (const float*)d_in[7];
  const float* g2  = (const float*)d_in[8];
  const float* be2 = (const float*)d_in[9];
  const float* w3  = (const float*)d_in[10];
  const float* b3  = (const float*)d_in[11];
  const float* dw  = (const float*)d_in[12];
  const float* db  = (const float*)d_in[13];

  char* ws = (char*)d_ws;
  u16* G    = (u16*)(ws + OFF_G);
  u16* Gt   = (u16*)(ws + OFF_GT);
  float* U    = (float*)(ws + OFF_U);
  float* V    = (float*)(ws + OFF_V);
  float* cnm  = (float*)(ws + OFF_CNM);
  float* cnis = (float*)(ws + OFF_CNIS);
  float* bns1 = (float*)(ws + OFF_BNS);
  float* bns2 = bns1 + 512;
  float* pnp  = (float*)(ws + OFF_PNP);
  u16* cfh = (u16*)(ws + OFF_CFH);
  u16* cfl = (u16*)(ws + OFF_CFL);
  u16* sfh = (u16*)(ws + OFF_SFH);
  u16* sfl = (u16*)(ws + OFF_SFL);
  u16* snb = (u16*)(ws + OFF_SNB);
  float* tn  = (float*)(ws + OFF_TN);
  u16* tcp = (u16*)(ws + OFF_TCP);
  u16* w1p = (u16*)(ws + OFF_W1P);
  u16* w2p = (u16*)(ws + OFF_W2P);
  u16* w3p = (u16*)(ws + OFF_W3P);
  u16* wdp = (u16*)(ws + OFF_WDP);
  u16* pip = (u16*)(ws + OFF_PIP);
  float* z1  = (float*)(ws + OFF_Z1);
  u16*   a1p = (u16*)(ws + OFF_A1P);
  float* z2  = (float*)(ws + OFF_Z2);
  u16*   a2p = (u16*)(ws + OFF_A2P);
  u16*   t2p = (u16*)(ws + OFF_T2P);

  // one memset covers U,V (needed) + INC..CNIS (overwritten later) + BNS (needed)
  hipMemsetAsync(ws + OFF_U, 0, 84 << 10, stream);

  pack_all_k<<<1184, 256, 0, stream>>>(w1, w2, w3, dw, w1p, w2p, w3p, wdp);

  stats_k<<<2304, 256, 0, stream>>>(cf, sf, cnm, cnis, pnp);
  tsplit_k<<<dim3(16, 8, 4), 256, 0, stream>>>(cf, pnp, cfh, cfl, tcp, 0);
  tsplit_k<<<dim3(16, 8, 4), 256, 0, stream>>>(sf, pnp, sfh, sfl, snb, 1);

  cgemm_k<<<dim3(8, 8, 4), 256, 0, stream>>>(cfh, cfl, sfh, sfl, G);
  trans_k<<<dim3(16, 16, 4), 256, 0, stream>>>(G, Gt);

  for (int it = 0; it < 20; ++it){
    lse_k<<<1024, 256, 0, stream>>>(G,  V, U);
    lse_k<<<1024, 256, 0, stream>>>(Gt, U, V);
  }

  pi_k<<<4096, 256, 0, stream>>>(G, U, V, pip);
  tgemm_k<<<dim3(16, 4, 4), 256, 0, stream>>>(pip, snb, tn, tcp);

  conv_k<1024, 256, 2, 0><<<dim3(16, 4, 8), 256, 0, stream>>>(
      tcp, w1p, nullptr, z1, nullptr, nullptr, nullptr, nullptr, nullptr);
  bn_stats_k<<<dim3(4, 8), 256, 0, stream>>>(z1, b1, bns1);
  bn_apply_k<<<1024, 256, 0, stream>>>(z1, b1, bns1, g1, be1, a1p);

  conv_k<256, 256, 2, 0><<<dim3(16, 4, 8), 256, 0, stream>>>(
      a1p, w2p, nullptr, z2, nullptr, nullptr, nullptr, nullptr, nullptr);
  bn_stats_k<<<dim3(4, 8), 256, 0, stream>>>(z2, b2, bns2);
  bn_apply_k<<<1024, 256, 0, stream>>>(z2, b2, bns2, g2, be2, a2p);

  conv_k<256, 512, 1, 1><<<dim3(16, 8, 4), 256, 0, stream>>>(
      a2p, w3p, b3, nullptr, t2p, tcp, cnm, cnis, tn);

  dec_k<<<256, 256, 0, stream>>>(t2p, wdp, db, (float*)d_out);

  (void)in_sizes; (void)n_in; (void)out_size; (void)ws_size;
}

// Round 9
// 418.905 us; speedup vs baseline: 1.0606x; 1.0606x over previous
//
#include <hip/hip_runtime.h>

typedef unsigned short u16;
typedef unsigned int u32;
typedef float f32x4 __attribute__((ext_vector_type(4)));
typedef short bf16x8 __attribute__((ext_vector_type(8)));   // 8 bf16 bit-patterns (4 VGPRs)

#define DEV static __device__ __forceinline__

DEV float bf2f(u16 u){ union{float f; u32 i;} x; x.i = ((u32)u) << 16; return x.f; }
DEV u16 f2bf(float f){ union{float f; u32 i;} x; x.f = f; u32 u = x.i;
  return (u16)((u + 0x7fffu + ((u >> 16) & 1u)) >> 16); }           // RNE
DEV u16 f2h(float f){ _Float16 h = (_Float16)f; u16 u; __builtin_memcpy(&u, &h, 2); return u; }
DEV float h2f(u16 u){ _Float16 h; __builtin_memcpy(&h, &u, 2); return (float)h; }
DEV uint4 pack8(const u16* s){ uint4 v;
  v.x = (u32)s[0] | ((u32)s[1]<<16); v.y = (u32)s[2] | ((u32)s[3]<<16);
  v.z = (u32)s[4] | ((u32)s[5]<<16); v.w = (u32)s[6] | ((u32)s[7]<<16); return v; }
DEV f32x4 mfma16(bf16x8 a, bf16x8 b, f32x4 c){
  return __builtin_amdgcn_mfma_f32_16x16x32_bf16(a, b, c, 0, 0, 0);
}
DEV bf16x8 ldfrag(const u16* p){ return *(const bf16x8*)p; }

constexpr float SCL = 144.269504088896341f;    // 100*log2(e) = 1/(eps*ln2), eps=0.01
constexpr float LOG2MU = -9.99998522680257f;   // log2(1/1024 + 1e-8)

// ---------------- workspace layout ----------------
// Packed activation layout AP[ck][row=b*1024+px][32]: elem = (ck*4096+row)*32+c
constexpr size_t MB = 1ull << 20;
constexpr size_t OFF_G    = 0;                 // f16 [4][1024][1024]
constexpr size_t OFF_GT   = 8*MB;              // f16 transpose
constexpr size_t OFF_U    = 16*MB;             // fp32 [4][1024]
constexpr size_t OFF_V    = OFF_U   + (16<<10);
constexpr size_t OFF_INC  = OFF_V   + (16<<10);// (unused, layout keep)
constexpr size_t OFF_INS  = OFF_INC + (16<<10);
constexpr size_t OFF_CNM  = OFF_INS + (16<<10);
constexpr size_t OFF_CNIS = OFF_CNM + (8<<10);
constexpr size_t OFF_BNS  = OFF_CNIS+ (8<<10);
constexpr size_t OFF_PNP  = OFF_BNS + (4<<10); // pixel-norm partials [2][8][4096] f32 = 256 KB
constexpr size_t OFF_CFH  = 17*MB;             // bf16 [4][1024][512]
constexpr size_t OFF_CFL  = 21*MB;
constexpr size_t OFF_SFH  = 25*MB;
constexpr size_t OFF_SFL  = 29*MB;
constexpr size_t OFF_SNB  = 33*MB;             // bf16 style NCHW [4][512][1024]
constexpr size_t OFF_TN   = 37*MB;             // fp32 t NHWC [4][1024][512]
constexpr size_t OFF_TCP  = 45*MB;             // bf16 packed concat: 32 chunks
constexpr size_t OFF_W1P  = 53*MB;             // frag-order bf16 weights
constexpr size_t OFF_W2P  = OFF_W1P + 9*256*1024*2;
constexpr size_t OFF_W3P  = OFF_W2P + 9*256*256*2;
constexpr size_t OFF_WDP  = OFF_W3P + 9*512*256*2;   // [9][16][512]
constexpr size_t OFF_PIP  = 62*MB;             // bf16 pi packed [4][1024][1024]
// reuse (dead after cgemm/tgemm):
constexpr size_t OFF_Z1  = 17*MB;              // fp32 partials 2x[4096][256]
constexpr size_t OFF_A1P = 25*MB;              // packed bf16, 8 chunks
constexpr size_t OFF_Z2  = 27*MB;              // fp32 partials 2x[4096][256]
constexpr size_t OFF_A2P = 35*MB;              // packed bf16, 8 chunks
constexpr size_t OFF_T2P = 17*MB;              // packed bf16, 16 chunks (z1 dead)

// ---------------- weight pack: coalesced via LDS ----------------
__global__ void pack_all_k(const float* __restrict__ w1, const float* __restrict__ w2,
                           const float* __restrict__ w3, const float* __restrict__ wd,
                           u16* __restrict__ w1p, u16* __restrict__ w2p,
                           u16* __restrict__ w3p, u16* __restrict__ wdp){
  int blk = blockIdx.x;
  const float* w; u16* wp; int CI, NCK, rel;
  if (blk < 512){ w = w1; wp = w1p; CI = 1024; NCK = 32; rel = blk; }
  else if (blk < 640){ w = w2; wp = w2p; CI = 256; NCK = 8; rel = blk - 512; }
  else if (blk < 896){ w = w3; wp = w3p; CI = 256; NCK = 8; rel = blk - 640; }
  else {                                        // decoder: small scatter path
    int o = (blk - 896)*256 + threadIdx.x;      // 288 blocks x 256 = 73728
    int ci = o & 511; int r = o >> 9; int co = r & 15; int tap = r >> 4;
    wdp[o] = f2bf((co < 3) ? wd[(size_t)(co*512 + ci)*9 + tap] : 0.f);
    return;
  }
  int g = rel / NCK, ck = rel % NCK;
  __shared__ float L[16*288];                   // [co][ci_local*9+tap], 18.4 KB
  const float* base = w + ((size_t)(g*16)*CI + ck*32)*9;
  #pragma unroll
  for (int i = 0; i < 18; ++i){
    int idx = i*256 + threadIdx.x;              // 0..4607
    int row = idx / 288, col = idx - row*288;
    L[row*288 + col] = base[(size_t)row*CI*9 + col];
  }
  __syncthreads();
  u16* dst = wp + ((size_t)(g*NCK + ck)*9)*512;
  #pragma unroll
  for (int i = 0; i < 18; ++i){
    int j = i*256 + threadIdx.x;                // contiguous dest
    int tap = j >> 9, r = j & 511, lane = r >> 3, e = r & 7;
    int co = lane & 15, cil = ((lane >> 4) & 3)*8 + e;
    dst[j] = f2bf(L[co*288 + cil*9 + tap]);     // stride-9 LDS read: conflict-free
  }
}

// ---------------- fused stats: chan_stats (blocks 0..2047) + pix_part (2048..2303)
__global__ void stats_k(const float* __restrict__ cf, const float* __restrict__ sf,
                        float* __restrict__ cnm, float* __restrict__ cnis,
                        float* __restrict__ part){
  int blk = blockIdx.x;
  if (blk < 2048){                              // content channel stats
    int bd = blk;
    float4 v = ((const float4*)(cf + (size_t)bd*1024))[threadIdx.x];
    float s = v.x+v.y+v.z+v.w;
    float q = v.x*v.x+v.y*v.y+v.z*v.z+v.w*v.w;
    #pragma unroll
    for (int m = 32; m >= 1; m >>= 1){ s += __shfl_xor(s, m, 64); q += __shfl_xor(q, m, 64); }
    __shared__ float ls[4], lq[4];
    int w = threadIdx.x >> 6;
    if ((threadIdx.x & 63) == 0){ ls[w] = s; lq[w] = q; }
    __syncthreads();
    if (threadIdx.x == 0){
      float S = ls[0]+ls[1]+ls[2]+ls[3], Q = lq[0]+lq[1]+lq[2]+lq[3];
      float mean = S * (1.f/1024.f);
      float var  = Q * (1.f/1024.f) - mean*mean;
      cnm[bd] = mean; cnis[bd] = rsqrtf(var + 1e-5f);
    }
    return;
  }
  int rel = blk - 2048;                         // pixel-norm partials
  int x = rel & 15, y = (rel >> 4) & 7, src = rel >> 7;
  const float* in = src ? sf : cf;
  int p = x*256 + threadIdx.x;
  int b = p >> 10, pp = p & 1023;
  const float* base = in + ((size_t)(b*512 + y*64))*1024 + pp;
  float s = 0.f;
  #pragma unroll 8
  for (int d = 0; d < 64; ++d){ float xx = base[(size_t)d*1024]; s += xx*xx; }
  part[((size_t)(src*8 + y))*4096 + p] = s;
}

// NCHW fp32 -> points [p][d] bf16 hi/lo split (+aux); inv-norm computed from partials
__global__ void tsplit_k(const float* __restrict__ src, const float* __restrict__ pnp,
                         u16* __restrict__ hi, u16* __restrict__ lo,
                         u16* __restrict__ aux, int is_style){
  __shared__ float tile[64][65];
  int b = blockIdx.z, p0 = blockIdx.x*64, d0 = blockIdx.y*64;
  int r = threadIdx.x >> 2, c0 = (threadIdx.x & 3) * 16;
  const float* sp = src + ((size_t)(b*512 + d0 + r))*1024 + p0 + c0;
  float v[16];
  #pragma unroll
  for (int e = 0; e < 4; ++e){
    float4 t4 = ((const float4*)sp)[e];
    v[e*4+0]=t4.x; v[e*4+1]=t4.y; v[e*4+2]=t4.z; v[e*4+3]=t4.w;
  }
  #pragma unroll
  for (int j = 0; j < 16; ++j) tile[r][c0+j] = v[j];
  if (is_style){
    u16 t16[16];
    #pragma unroll
    for (int j = 0; j < 16; ++j) t16[j] = f2bf(v[j]);
    uint4* ap = (uint4*)(aux + ((size_t)(b*512 + d0 + r))*1024 + p0 + c0);
    ap[0] = pack8(t16); ap[1] = pack8(t16+8);
  }
  __syncthreads();
  int pr = r, dc0 = c0;
  float inv;
  {
    const float* pp = pnp + (size_t)(is_style ? 8*4096 : 0) + ((b<<10) + p0 + pr);
    float s = 0.f;
    #pragma unroll
    for (int j = 0; j < 8; ++j) s += pp[j*4096];
    inv = rsqrtf(s);
  }
  u16 h16[16], l16[16], t16[16];
  #pragma unroll
  for (int j = 0; j < 16; ++j){
    float x = tile[dc0+j][pr];
    t16[j] = f2bf(x);
    float xn = x * inv;
    u16 h = f2bf(xn);
    h16[j] = h;
    l16[j] = f2bf(xn - bf2f(h));
  }
  size_t orow = (size_t)((b<<10) + p0 + pr);
  uint4* hp = (uint4*)(hi + orow*512 + d0 + dc0);
  uint4* lp = (uint4*)(lo + orow*512 + d0 + dc0);
  hp[0] = pack8(h16); hp[1] = pack8(h16+8);
  lp[0] = pack8(l16); lp[1] = pack8(l16+8);
  if (!is_style){                              // content -> packed tc chunks 16..31
    int D = d0 + dc0;
    size_t off = ((size_t)(16 + (D>>5))*4096 + orow)*32 + (D&31);
    *(uint4*)(aux + off)     = pack8(t16);
    *(uint4*)(aux + off + 8) = pack8(t16+8);
  }
}

// ---------------- C-GEMM: G = (cfn.sfn - 1)*SCL, split bf16
// Direct staging (no reg prefetch — R8 showed it regressed this kernel).
// Epilogue transposes C through LDS -> fully-coalesced uint4 stores
// (R8 showed 2-byte scattered stores caused 7.5x write amplification).
__global__ __launch_bounds__(256) void cgemm_k(const u16* __restrict__ cfh, const u16* __restrict__ cfl,
        const u16* __restrict__ sfh, const u16* __restrict__ sfl,
        u16* __restrict__ G){
  __shared__ __align__(16) u16 SH[4*128*40];   // 40 KB: staging; epilogue reuses (needs 34 KB)
  u16* Ah = SH;          u16* Al = SH + 5120;
  u16* Bh = SH + 10240;  u16* Bl = SH + 15360;
  int b = blockIdx.z;
  size_t abase = ((size_t)((b<<10) + blockIdx.x*128))*512;
  size_t bbase = ((size_t)((b<<10) + blockIdx.y*128))*512;
  int lane = threadIdx.x & 63, wid = threadIdx.x >> 6;
  int wm = (wid >> 1)*64, wn = (wid & 1)*64;
  int fr = lane & 15, qd = lane >> 4;
  int sr = threadIdx.x >> 1, sc = (threadIdx.x & 1)*16;
  f32x4 acc[4][4] = {};
  for (int kk = 0; kk < 512; kk += 32){
    size_t g0 = (size_t)sr*512 + kk + sc;
    *(uint4*)&Ah[sr*40+sc]   = *(const uint4*)(cfh + abase + g0);
    *(uint4*)&Ah[sr*40+sc+8] = *(const uint4*)(cfh + abase + g0 + 8);
    *(uint4*)&Al[sr*40+sc]   = *(const uint4*)(cfl + abase + g0);
    *(uint4*)&Al[sr*40+sc+8] = *(const uint4*)(cfl + abase + g0 + 8);
    *(uint4*)&Bh[sr*40+sc]   = *(const uint4*)(sfh + bbase + g0);
    *(uint4*)&Bh[sr*40+sc+8] = *(const uint4*)(sfh + bbase + g0 + 8);
    *(uint4*)&Bl[sr*40+sc]   = *(const uint4*)(sfl + bbase + g0);
    *(uint4*)&Bl[sr*40+sc+8] = *(const uint4*)(sfl + bbase + g0 + 8);
    __syncthreads();
    bf16x8 bhf[4], blf[4];
    #pragma unroll
    for (int ni = 0; ni < 4; ++ni){
      bhf[ni] = ldfrag(&Bh[(wn + ni*16 + fr)*40 + qd*8]);
      blf[ni] = ldfrag(&Bl[(wn + ni*16 + fr)*40 + qd*8]);
    }
    #pragma unroll
    for (int mi = 0; mi < 4; ++mi){
      bf16x8 ah = ldfrag(&Ah[(wm + mi*16 + fr)*40 + qd*8]);
      bf16x8 al = ldfrag(&Al[(wm + mi*16 + fr)*40 + qd*8]);
      #pragma unroll
      for (int ni = 0; ni < 4; ++ni){
        acc[mi][ni] = mfma16(ah, bhf[ni], acc[mi][ni]);
        acc[mi][ni] = mfma16(ah, blf[ni], acc[mi][ni]);
        acc[mi][ni] = mfma16(al, bhf[ni], acc[mi][ni]);
      }
    }
    __syncthreads();
  }
  // epilogue: C tile -> LDS (f16, row stride 136) -> coalesced uint4 stores
  #pragma unroll
  for (int mi = 0; mi < 4; ++mi)
    #pragma unroll
    for (int ni = 0; ni < 4; ++ni)
      #pragma unroll
      for (int rg = 0; rg < 4; ++rg){
        int r = wm + mi*16 + qd*4 + rg;
        int c = wn + ni*16 + fr;
        SH[r*136 + c] = f2h((acc[mi][ni][rg] - 1.f) * SCL);
      }
  __syncthreads();
  size_t gb = (((size_t)b) << 20) + (size_t)(blockIdx.x*128)*1024 + blockIdx.y*128;
  #pragma unroll
  for (int i = 0; i < 8; ++i){
    int idx = i*256 + threadIdx.x;              // 0..2047 uint4s of the tile
    int r = idx >> 4, c4 = idx & 15;
    *(uint4*)(G + gb + (size_t)r*1024 + c4*8) = *(const uint4*)&SH[r*136 + c4*8];
  }
}

// ---------------- f16 64x64 tiled transpose: Gt[b][j][i] = G[b][i][j]
__global__ __launch_bounds__(256) void trans_k(const u16* __restrict__ G, u16* __restrict__ Gt){
  __shared__ u16 T[64][66];
  int b = blockIdx.z, x0 = blockIdx.x*64, y0 = blockIdx.y*64;
  int t = threadIdx.x;
  int r = t >> 2, c0 = (t & 3)*16;
  const u16* src = G + (((size_t)((b<<10) + y0 + r)) << 10) + x0 + c0;
  uint4 v0 = ((const uint4*)src)[0], v1 = ((const uint4*)src)[1];
  u32 w[8] = {v0.x,v0.y,v0.z,v0.w,v1.x,v1.y,v1.z,v1.w};
  #pragma unroll
  for (int k = 0; k < 8; ++k){
    T[r][c0 + 2*k]     = (u16)(w[k] & 0xffffu);
    T[r][c0 + 2*k + 1] = (u16)(w[k] >> 16);
  }
  __syncthreads();
  u16 o[16];
  #pragma unroll
  for (int k = 0; k < 16; ++k) o[k] = T[c0 + k][r];
  u16* dst = Gt + (((size_t)((b<<10) + x0 + r)) << 10) + y0 + c0;
  ((uint4*)dst)[0] = pack8(o);
  ((uint4*)dst)[1] = pack8(o + 8);
}

// ---------------- Sinkhorn log2-domain pass over f16 matrix
__global__ void lse_k(const u16* __restrict__ M, const float* __restrict__ addv,
                      float* __restrict__ outv){
  int row = blockIdx.x*4 + (threadIdx.x >> 6);
  int lane = threadIdx.x & 63;
  int b = row >> 10;
  const uint4* r4 = (const uint4*)(M + ((size_t)row << 10));
  const float4* a4 = (const float4*)(addv + ((size_t)b << 10));
  float x[16]; float mx = -3.0e38f;
  #pragma unroll
  for (int e = 0; e < 2; ++e){
    uint4 g = r4[lane + 64*e];
    float4 a0 = a4[2*(lane + 64*e)];
    float4 a1 = a4[2*(lane + 64*e) + 1];
    u32 w[4] = {g.x, g.y, g.z, g.w};
    float av[8] = {a0.x,a0.y,a0.z,a0.w,a1.x,a1.y,a1.z,a1.w};
    #pragma unroll
    for (int i = 0; i < 8; ++i){
      u16 hv = (u16)((i & 1) ? (w[i>>1] >> 16) : (w[i>>1] & 0xffffu));
      float t = h2f(hv) + av[i];
      x[e*8+i] = t;
      mx = fmaxf(mx, t);
    }
  }
  #pragma unroll
  for (int m = 32; m >= 1; m >>= 1) mx = fmaxf(mx, __shfl_xor(mx, m, 64));
  float s = 0.f;
  #pragma unroll
  for (int i = 0; i < 16; ++i) s += exp2f(x[i] - mx);
  #pragma unroll
  for (int m = 32; m >= 1; m >>= 1) s += __shfl_xor(s, m, 64);
  if (lane == 0) outv[row] = LOG2MU - (mx + log2f(s));
}

// ---------------- pi materialization: pip[row][j] = bf16(2^(G+U+V+10))
__global__ void pi_k(const u16* __restrict__ G, const float* __restrict__ U,
                     const float* __restrict__ V, u16* __restrict__ pip){
  int row = blockIdx.x, b = row >> 10, t = threadIdx.x;
  float ur = U[row] + 10.f;                    // +10: fold pi * 1024
  uint2 g = ((const uint2*)(G + ((size_t)row << 10)))[t];
  float4 vv = ((const float4*)(V + ((size_t)b << 10)))[t];
  u16 o[4];
  o[0] = f2bf(exp2f(h2f((u16)(g.x & 0xffffu)) + vv.x + ur));
  o[1] = f2bf(exp2f(h2f((u16)(g.x >> 16))     + vv.y + ur));
  o[2] = f2bf(exp2f(h2f((u16)(g.y & 0xffffu)) + vv.z + ur));
  o[3] = f2bf(exp2f(h2f((u16)(g.y >> 16))     + vv.w + ur));
  uint2 pk; pk.x = (u32)o[0] | ((u32)o[1]<<16); pk.y = (u32)o[2] | ((u32)o[3]<<16);
  ((uint2*)(pip + ((size_t)row << 10)))[t] = pk;
}

// ---------------- t = pi @ sf: pure bf16 GEMM, 64p x 128d tiles, reg prefetch
__global__ __launch_bounds__(256) void tgemm_k(const u16* __restrict__ pip,
        const u16* __restrict__ snb, float* __restrict__ tn, u16* __restrict__ tcp){
  __shared__ __align__(16) u16 As[64*40], Bs[128*40];
  int b = blockIdx.z, p0 = blockIdx.x*64, d0 = blockIdx.y*128;
  int tid = threadIdx.x, lane = tid & 63, wid = tid >> 6;
  int wm = (wid >> 1)*32, wn = (wid & 1)*64;
  int fr = lane & 15, qd = lane >> 4;
  int a_r = tid >> 2, a_c = (tid & 3)*8;
  int b_r = tid >> 1, b_c = (tid & 1)*16;
  const u16* Arow = pip + (((size_t)((b<<10) + p0 + a_r)) << 10) + a_c;
  const u16* Brow = snb + (((size_t)(b*512 + d0 + b_r)) << 10) + b_c;
  uint4 pa, pb0, pb1;
  auto issue = [&](int kk){
    pa = *(const uint4*)(Arow + kk);
    const uint4* bp = (const uint4*)(Brow + kk);
    pb0 = bp[0]; pb1 = bp[1];
  };
  f32x4 acc[2][4] = {};
  issue(0);
  for (int kk = 0; kk < 1024; kk += 32){
    *(uint4*)&As[a_r*40 + a_c] = pa;
    *(uint4*)&Bs[b_r*40 + b_c] = pb0;
    *(uint4*)&Bs[b_r*40 + b_c + 8] = pb1;
    __syncthreads();
    if (kk + 32 < 1024) issue(kk + 32);
    bf16x8 bfr[4];
    #pragma unroll
    for (int ni = 0; ni < 4; ++ni) bfr[ni] = ldfrag(&Bs[(wn + ni*16 + fr)*40 + qd*8]);
    #pragma unroll
    for (int mi = 0; mi < 2; ++mi){
      bf16x8 afr = ldfrag(&As[(wm + mi*16 + fr)*40 + qd*8]);
      #pragma unroll
      for (int ni = 0; ni < 4; ++ni) acc[mi][ni] = mfma16(afr, bfr[ni], acc[mi][ni]);
    }
    __syncthreads();
  }
  #pragma unroll
  for (int mi = 0; mi < 2; ++mi)
    #pragma unroll
    for (int ni = 0; ni < 4; ++ni)
      #pragma unroll
      for (int rg = 0; rg < 4; ++rg){
        int p = p0 + wm + mi*16 + qd*4 + rg;
        int d = d0 + wn + ni*16 + fr;
        float vout = acc[mi][ni][rg];
        size_t ro = (size_t)((b<<10) + p);
        tn[ro*512 + d] = vout;
        tcp[((size_t)(d>>5)*4096 + ro)*32 + (d&31)] = f2bf(vout);
      }
}

// ---------------- implicit-GEMM 3x3 conv: packed activations, frag-order weights
template<int CI, int CO, int KSPLIT, int MODE>
__global__ __launch_bounds__(256) void conv_k(const u16* __restrict__ inp, const u16* __restrict__ wpk,
        const float* __restrict__ bias, float* __restrict__ fout, u16* __restrict__ bout,
        const u16* __restrict__ tcp, const float* __restrict__ cnm, const float* __restrict__ cnis,
        const float* __restrict__ tn){
  constexpr int NCK_TOT = CI/32, NCK = NCK_TOT/KSPLIT;
  __shared__ __align__(16) u16 As[128*40];
  int b = blockIdx.z & 3, ks = blockIdx.z >> 2;
  int c0 = blockIdx.y*64;
  int r0 = blockIdx.x*2;
  int tid = threadIdx.x, lane = tid & 63, wid = tid >> 6;
  int wm = (wid >> 1)*32, wn = (wid & 1)*32;
  int fr = lane & 15, qd = lane >> 4;
  int ck0 = ks*NCK;
  int hrow = tid >> 1;
  int ah = (tid & 1)*16;
  int gy = r0 - 1 + (hrow >> 5);
  bool a_ok = ((unsigned)gy < 32u);
  size_t arow = (size_t)(b<<10) + (r0-1)*32 + hrow;
  uint4 pa0 = {0,0,0,0}, pa1 = {0,0,0,0};
  auto issueA = [&](int ck){
    if (a_ok){
      const uint4* s = (const uint4*)(inp + ((size_t)(ck0+ck)*4096 + arow)*32 + ah);
      pa0 = s[0]; pa1 = s[1];
    }
  };
  int g0 = (c0 + wn) >> 4;
  const u16* wb0 = wpk + ((size_t)(g0    )*NCK_TOT + ck0)*9*512 + lane*8;
  const u16* wb1 = wpk + ((size_t)(g0 + 1)*NCK_TOT + ck0)*9*512 + lane*8;

  f32x4 acc[2][2] = {};
  issueA(0);
  for (int ck = 0; ck < NCK; ++ck){
    *(uint4*)&As[hrow*40 + ah]     = pa0;
    *(uint4*)&As[hrow*40 + ah + 8] = pa1;
    __syncthreads();
    if (ck + 1 < NCK) issueA(ck + 1);
    #pragma unroll
    for (int tap = 0; tap < 9; ++tap){
      const int dy = tap/3 - 1, dx = tap%3 - 1;
      bf16x8 bf0 = ldfrag(wb0 + (size_t)(ck*9 + tap)*512);
      bf16x8 bf1 = ldfrag(wb1 + (size_t)(ck*9 + tap)*512);
      #pragma unroll
      for (int mi = 0; mi < 2; ++mi){
        int p0w = wm + mi*16;
        int pcol = (p0w & 31) + fr + dx;
        int lr = (p0w >> 5) + dy + 1;
        bool okc = (unsigned)pcol < 32u;
        bf16x8 af = ldfrag(&As[(lr*32 + (okc ? pcol : 0))*40 + qd*8]);
        if (!okc) af = bf16x8(0);
        acc[mi][0] = mfma16(af, bf0, acc[mi][0]);
        acc[mi][1] = mfma16(af, bf1, acc[mi][1]);
      }
    }
    __syncthreads();
  }
  #pragma unroll
  for (int mi = 0; mi < 2; ++mi)
    #pragma unroll
    for (int ni = 0; ni < 2; ++ni)
      #pragma unroll
      for (int rg = 0; rg < 4; ++rg){
        int pp = blockIdx.x*64 + wm + mi*16 + qd*4 + rg;
        int cc = c0 + wn + ni*16 + fr;
        float v = acc[mi][ni][rg];
        size_t ro = (size_t)((b<<10) + pp);
        if (MODE == 0){
          fout[(size_t)ks*4096*CO + ro*CO + cc] = v;
        } else {
          float alpha = v + bias[cc];
          float cn = (bf2f(tcp[((size_t)(16 + (cc>>5))*4096 + ro)*32 + (cc&31)])
                      - cnm[(b<<9) + cc]) * cnis[(b<<9) + cc];
          bout[((size_t)(cc>>5)*4096 + ro)*32 + (cc&31)] = f2bf(alpha*cn + tn[ro*512 + cc]);
        }
      }
}

// ---------------- decoder conv (512 -> 3): VALU reduction over packed t2
__global__ __launch_bounds__(256) void dec_k(const u16* __restrict__ t2p, const u16* __restrict__ wdp,
                                             const float* __restrict__ db, float* __restrict__ out){
  __shared__ float wlds[3*4608];
  int tid = threadIdx.x;
  for (int k = tid; k < 3*4608; k += 256){
    int c = k / 4608, rem = k - c*4608;
    int tap = rem >> 9, ci = rem & 511;
    wlds[k] = bf2f(wdp[(size_t)(tap*16 + c)*512 + ci]);
  }
  __syncthreads();
  int b = blockIdx.x >> 6;
  int p = ((blockIdx.x & 63) << 4) + (tid >> 4);
  int sub = tid & 15;
  int py = p >> 5, px = p & 31;
  float a0 = 0.f, a1 = 0.f, a2 = 0.f;
  for (int tap = 0; tap < 9; ++tap){
    int sy = py + tap/3 - 1, sx = px + tap%3 - 1;
    if (((unsigned)sy < 32u) && ((unsigned)sx < 32u)){
      size_t row = (size_t)((b<<10) + (sy<<5) + sx);
      const float* w0 = wlds + tap*512;
      #pragma unroll
      for (int j = 0; j < 4; ++j){
        int ci0 = j*128 + sub*8;
        uint4 v = *(const uint4*)(t2p + ((size_t)(ci0>>5)*4096 + row)*32 + (ci0&31));
        u32 ww[4] = {v.x, v.y, v.z, v.w};
        #pragma unroll
        for (int e = 0; e < 8; ++e){
          float x = bf2f((u16)((e & 1) ? (ww[e>>1] >> 16) : (ww[e>>1] & 0xffffu)));
          a0 += x * w0[ci0 + e];
          a1 += x * w0[4608 + ci0 + e];
          a2 += x * w0[9216 + ci0 + e];
        }
      }
    }
  }
  #pragma unroll
  for (int m = 8; m >= 1; m >>= 1){
    a0 += __shfl_xor(a0, m, 64);
    a1 += __shfl_xor(a1, m, 64);
    a2 += __shfl_xor(a2, m, 64);
  }
  if (sub == 0){
    out[((size_t)(b*3 + 0) << 10) + p] = a0 + db[0];
    out[((size_t)(b*3 + 1) << 10) + p] = a1 + db[1];
    out[((size_t)(b*3 + 2) << 10) + p] = a2 + db[2];
  }
}

// ---------------- BN over K-split partials: x = relu(za+zb+bias) ----------------
__global__ void bn_stats_k(const float* __restrict__ z, const float* __restrict__ bias,
                           float* __restrict__ sums){
  int c = blockIdx.x*64 + (threadIdx.x & 63);
  int w = threadIdx.x >> 6;
  int rbase = blockIdx.y*512 + w*128;
  float bi = bias[c];
  float s = 0.f, q = 0.f;
  for (int i = 0; i < 128; ++i){
    size_t ro = (size_t)(rbase + i)*256 + c;
    float x = fmaxf(z[ro] + z[4096*256 + ro] + bi, 0.f);
    s += x; q += x*x;
  }
  __shared__ float ls[4][64], lq[4][64];
  ls[w][threadIdx.x & 63] = s; lq[w][threadIdx.x & 63] = q;
  __syncthreads();
  if (threadIdx.x < 64){
    float S = ls[0][threadIdx.x]+ls[1][threadIdx.x]+ls[2][threadIdx.x]+ls[3][threadIdx.x];
    float Q = lq[0][threadIdx.x]+lq[1][threadIdx.x]+lq[2][threadIdx.x]+lq[3][threadIdx.x];
    atomicAdd(&sums[blockIdx.x*64 + threadIdx.x], S);
    atomicAdd(&sums[256 + blockIdx.x*64 + threadIdx.x], Q);
  }
}

// bn_apply with inline finalize
__global__ void bn_apply_k(const float* __restrict__ z, const float* __restrict__ bias,
                           const float* __restrict__ sums, const float* __restrict__ gamma,
                           const float* __restrict__ beta, u16* __restrict__ ap){
  int idx = blockIdx.x*256 + threadIdx.x;
  float4 va = ((const float4*)z)[idx];
  float4 vb = ((const float4*)(z + 4096*256))[idx];
  int row = idx >> 6;
  int cc0 = (idx << 2) & 255;
  float e[4] = {va.x+vb.x, va.y+vb.y, va.z+vb.z, va.w+vb.w};
  u16 o[4];
  #pragma unroll
  for (int k = 0; k < 4; ++k){
    int c = cc0 + k;
    float mean = sums[c] * (1.f/4096.f);
    float var  = sums[256 + c] * (1.f/4096.f) - mean*mean;
    float sc = gamma[c] * rsqrtf(var + 1e-5f);
    float sh = beta[c] - mean*sc;
    float x = fmaxf(e[k] + bias[c], 0.f);
    o[k] = f2bf(x*sc + sh);
  }
  uint2 pk; pk.x = (u32)o[0] | ((u32)o[1]<<16); pk.y = (u32)o[2] | ((u32)o[3]<<16);
  *(uint2*)(ap + ((size_t)(cc0>>5)*4096 + row)*32 + (cc0&31)) = pk;
}

// ---------------- launch ----------------
extern "C" void kernel_launch(void* const* d_in, const int* in_sizes, int n_in,
                              void* d_out, int out_size, void* d_ws, size_t ws_size,
                              hipStream_t stream){
  const float* cf  = (const float*)d_in[0];
  const float* sf  = (const float*)d_in[1];
  const float* w1  = (const float*)d_in[2];
  const float* b1  = (const float*)d_in[3];
  const float* g1  = (const float*)d_in[4];
  const float* be1 = (const float*)d_in[5];
  const float* w2  = (const float*)d_in[6];
  const float* b2  = (const float*)d_in[7];
  const float* g2  = (const float*)d_in[8];
  const float* be2 = (const float*)d_in[9];
  const float* w3  = (const float*)d_in[10];
  const float* b3  = (const float*)d_in[11];
  const float* dw  = (const float*)d_in[12];
  const float* db  = (const float*)d_in[13];

  char* ws = (char*)d_ws;
  u16* G    = (u16*)(ws + OFF_G);
  u16* Gt   = (u16*)(ws + OFF_GT);
  float* U    = (float*)(ws + OFF_U);
  float* V    = (float*)(ws + OFF_V);
  float* cnm  = (float*)(ws + OFF_CNM);
  float* cnis = (float*)(ws + OFF_CNIS);
  float* bns1 = (float*)(ws + OFF_BNS);
  float* bns2 = bns1 + 512;
  float* pnp  = (float*)(ws + OFF_PNP);
  u16* cfh = (u16*)(ws + OFF_CFH);
  u16* cfl = (u16*)(ws + OFF_CFL);
  u16* sfh = (u16*)(ws + OFF_SFH);
  u16* sfl = (u16*)(ws + OFF_SFL);
  u16* snb = (u16*)(ws + OFF_SNB);
  float* tn  = (float*)(ws + OFF_TN);
  u16* tcp = (u16*)(ws + OFF_TCP);
  u16* w1p = (u16*)(ws + OFF_W1P);
  u16* w2p = (u16*)(ws + OFF_W2P);
  u16* w3p = (u16*)(ws + OFF_W3P);
  u16* wdp = (u16*)(ws + OFF_WDP);
  u16* pip = (u16*)(ws + OFF_PIP);
  float* z1  = (float*)(ws + OFF_Z1);
  u16*   a1p = (u16*)(ws + OFF_A1P);
  float* z2  = (float*)(ws + OFF_Z2);
  u16*   a2p = (u16*)(ws + OFF_A2P);
  u16*   t2p = (u16*)(ws + OFF_T2P);

  // one memset covers U,V (needed) + INC..CNIS (overwritten later) + BNS (needed)
  hipMemsetAsync(ws + OFF_U, 0, 84 << 10, stream);

  pack_all_k<<<1184, 256, 0, stream>>>(w1, w2, w3, dw, w1p, w2p, w3p, wdp);

  stats_k<<<2304, 256, 0, stream>>>(cf, sf, cnm, cnis, pnp);
  tsplit_k<<<dim3(16, 8, 4), 256, 0, stream>>>(cf, pnp, cfh, cfl, tcp, 0);
  tsplit_k<<<dim3(16, 8, 4), 256, 0, stream>>>(sf, pnp, sfh, sfl, snb, 1);

  cgemm_k<<<dim3(8, 8, 4), 256, 0, stream>>>(cfh, cfl, sfh, sfl, G);
  trans_k<<<dim3(16, 16, 4), 256, 0, stream>>>(G, Gt);

  for (int it = 0; it < 20; ++it){
    lse_k<<<1024, 256, 0, stream>>>(G,  V, U);
    lse_k<<<1024, 256, 0, stream>>>(Gt, U, V);
  }

  pi_k<<<4096, 256, 0, stream>>>(G, U, V, pip);
  tgemm_k<<<dim3(16, 4, 4), 256, 0, stream>>>(pip, snb, tn, tcp);

  conv_k<1024, 256, 2, 0><<<dim3(16, 4, 8), 256, 0, stream>>>(
      tcp, w1p, nullptr, z1, nullptr, nullptr, nullptr, nullptr, nullptr);
  bn_stats_k<<<dim3(4, 8), 256, 0, stream>>>(z1, b1, bns1);
  bn_apply_k<<<1024, 256, 0, stream>>>(z1, b1, bns1, g1, be1, a1p);

  conv_k<256, 256, 2, 0><<<dim3(16, 4, 8), 256, 0, stream>>>(
      a1p, w2p, nullptr, z2, nullptr, nullptr, nullptr, nullptr, nullptr);
  bn_stats_k<<<dim3(4, 8), 256, 0, stream>>>(z2, b2, bns2);
  bn_apply_k<<<1024, 256, 0, stream>>>(z2, b2, bns2, g2, be2, a2p);

  conv_k<256, 512, 1, 1><<<dim3(16, 8, 4), 256, 0, stream>>>(
      a2p, w3p, b3, nullptr, t2p, tcp, cnm, cnis, tn);

  dec_k<<<256, 256, 0, stream>>>(t2p, wdp, db, (float*)d_out);

  (void)in_sizes; (void)n_in; (void)out_size; (void)ws_size;
}

// Round 10
// 405.665 us; speedup vs baseline: 1.0952x; 1.0326x over previous
//
#include <hip/hip_runtime.h>

typedef unsigned short u16;
typedef unsigned int u32;
typedef float f32x4 __attribute__((ext_vector_type(4)));
typedef short bf16x8 __attribute__((ext_vector_type(8)));   // 8 bf16 bit-patterns (4 VGPRs)

#define DEV static __device__ __forceinline__

DEV float bf2f(u16 u){ union{float f; u32 i;} x; x.i = ((u32)u) << 16; return x.f; }
DEV u16 f2bf(float f){ union{float f; u32 i;} x; x.f = f; u32 u = x.i;
  return (u16)((u + 0x7fffu + ((u >> 16) & 1u)) >> 16); }           // RNE
DEV u16 f2h(float f){ _Float16 h = (_Float16)f; u16 u; __builtin_memcpy(&u, &h, 2); return u; }
DEV float h2f(u16 u){ _Float16 h; __builtin_memcpy(&h, &u, 2); return (float)h; }
DEV uint4 pack8(const u16* s){ uint4 v;
  v.x = (u32)s[0] | ((u32)s[1]<<16); v.y = (u32)s[2] | ((u32)s[3]<<16);
  v.z = (u32)s[4] | ((u32)s[5]<<16); v.w = (u32)s[6] | ((u32)s[7]<<16); return v; }
DEV f32x4 mfma16(bf16x8 a, bf16x8 b, f32x4 c){
  return __builtin_amdgcn_mfma_f32_16x16x32_bf16(a, b, c, 0, 0, 0);
}
DEV bf16x8 ldfrag(const u16* p){ return *(const bf16x8*)p; }

constexpr float SCL = 144.269504088896341f;    // 100*log2(e) = 1/(eps*ln2), eps=0.01
constexpr float LOG2MU = -9.99998522680257f;   // log2(1/1024 + 1e-8)

// ---------------- workspace layout ----------------
// Packed activation layout AP[ck][row=b*1024+px][32]: elem = (ck*4096+row)*32+c
constexpr size_t MB = 1ull << 20;
constexpr size_t OFF_G    = 0;                 // f16 [4][1024][1024]
constexpr size_t OFF_GT   = 8*MB;              // f16 transpose
constexpr size_t OFF_U    = 16*MB;             // fp32 [4][1024]
constexpr size_t OFF_V    = OFF_U   + (16<<10);
constexpr size_t OFF_INC  = OFF_V   + (16<<10);// (unused, layout keep)
constexpr size_t OFF_INS  = OFF_INC + (16<<10);
constexpr size_t OFF_CNM  = OFF_INS + (16<<10);
constexpr size_t OFF_CNIS = OFF_CNM + (8<<10);
constexpr size_t OFF_BNS  = OFF_CNIS+ (8<<10);
constexpr size_t OFF_PNP  = OFF_BNS + (4<<10); // pixel-norm partials [2][8][4096] f32 = 256 KB
constexpr size_t OFF_CFH  = 17*MB;             // bf16 [4][1024][512]
constexpr size_t OFF_CFL  = 21*MB;
constexpr size_t OFF_SFH  = 25*MB;
constexpr size_t OFF_SFL  = 29*MB;
constexpr size_t OFF_SNB  = 33*MB;             // bf16 style NCHW [4][512][1024]
constexpr size_t OFF_TN   = 37*MB;             // fp32 t NHWC [4][1024][512]
constexpr size_t OFF_TCP  = 45*MB;             // bf16 packed concat: 32 chunks
constexpr size_t OFF_W1P  = 53*MB;             // frag-order bf16 weights
constexpr size_t OFF_W2P  = OFF_W1P + 9*256*1024*2;
constexpr size_t OFF_W3P  = OFF_W2P + 9*256*256*2;
constexpr size_t OFF_WDP  = OFF_W3P + 9*512*256*2;   // [9][16][512]
constexpr size_t OFF_PIP  = 62*MB;             // bf16 pi packed [4][1024][1024]
// reuse (dead after cgemm/tgemm):
constexpr size_t OFF_Z1  = 17*MB;              // fp32 partials 2x[4096][256]
constexpr size_t OFF_A1P = 25*MB;              // packed bf16, 8 chunks
constexpr size_t OFF_Z2  = 27*MB;              // fp32 partials 2x[4096][256]
constexpr size_t OFF_A2P = 35*MB;              // packed bf16, 8 chunks
constexpr size_t OFF_T2P = 17*MB;              // packed bf16, 16 chunks (z1 dead)

// ---------------- weight pack: coalesced via LDS ----------------
__global__ void pack_all_k(const float* __restrict__ w1, const float* __restrict__ w2,
                           const float* __restrict__ w3, const float* __restrict__ wd,
                           u16* __restrict__ w1p, u16* __restrict__ w2p,
                           u16* __restrict__ w3p, u16* __restrict__ wdp){
  int blk = blockIdx.x;
  const float* w; u16* wp; int CI, NCK, rel;
  if (blk < 512){ w = w1; wp = w1p; CI = 1024; NCK = 32; rel = blk; }
  else if (blk < 640){ w = w2; wp = w2p; CI = 256; NCK = 8; rel = blk - 512; }
  else if (blk < 896){ w = w3; wp = w3p; CI = 256; NCK = 8; rel = blk - 640; }
  else {                                        // decoder: small scatter path
    int o = (blk - 896)*256 + threadIdx.x;      // 288 blocks x 256 = 73728
    int ci = o & 511; int r = o >> 9; int co = r & 15; int tap = r >> 4;
    wdp[o] = f2bf((co < 3) ? wd[(size_t)(co*512 + ci)*9 + tap] : 0.f);
    return;
  }
  int g = rel / NCK, ck = rel % NCK;
  __shared__ float L[16*288];                   // [co][ci_local*9+tap], 18.4 KB
  const float* base = w + ((size_t)(g*16)*CI + ck*32)*9;
  #pragma unroll
  for (int i = 0; i < 18; ++i){
    int idx = i*256 + threadIdx.x;              // 0..4607
    int row = idx / 288, col = idx - row*288;
    L[row*288 + col] = base[(size_t)row*CI*9 + col];
  }
  __syncthreads();
  u16* dst = wp + ((size_t)(g*NCK + ck)*9)*512;
  #pragma unroll
  for (int i = 0; i < 18; ++i){
    int j = i*256 + threadIdx.x;                // contiguous dest
    int tap = j >> 9, r = j & 511, lane = r >> 3, e = r & 7;
    int co = lane & 15, cil = ((lane >> 4) & 3)*8 + e;
    dst[j] = f2bf(L[co*288 + cil*9 + tap]);     // stride-9 LDS read: conflict-free
  }
}

// ---------------- fused stats: chan_stats (0..2047) + pix_part (2048..2303)
//                  + workspace zeroing (2304..2339, replaces memset dispatch)
__global__ void stats_k(const float* __restrict__ cf, const float* __restrict__ sf,
                        float* __restrict__ cnm, float* __restrict__ cnis,
                        float* __restrict__ part, float* __restrict__ zUV,
                        float* __restrict__ zBNS){
  int blk = blockIdx.x;
  if (blk < 2048){                              // content channel stats
    int bd = blk;
    float4 v = ((const float4*)(cf + (size_t)bd*1024))[threadIdx.x];
    float s = v.x+v.y+v.z+v.w;
    float q = v.x*v.x+v.y*v.y+v.z*v.z+v.w*v.w;
    #pragma unroll
    for (int m = 32; m >= 1; m >>= 1){ s += __shfl_xor(s, m, 64); q += __shfl_xor(q, m, 64); }
    __shared__ float ls[4], lq[4];
    int w = threadIdx.x >> 6;
    if ((threadIdx.x & 63) == 0){ ls[w] = s; lq[w] = q; }
    __syncthreads();
    if (threadIdx.x == 0){
      float S = ls[0]+ls[1]+ls[2]+ls[3], Q = lq[0]+lq[1]+lq[2]+lq[3];
      float mean = S * (1.f/1024.f);
      float var  = Q * (1.f/1024.f) - mean*mean;
      cnm[bd] = mean; cnis[bd] = rsqrtf(var + 1e-5f);
    }
    return;
  }
  if (blk < 2304){
    int rel = blk - 2048;                       // pixel-norm partials
    int x = rel & 15, y = (rel >> 4) & 7, src = rel >> 7;
    const float* in = src ? sf : cf;
    int p = x*256 + threadIdx.x;
    int b = p >> 10, pp = p & 1023;
    const float* base = in + ((size_t)(b*512 + y*64))*1024 + pp;
    float s = 0.f;
    #pragma unroll 8
    for (int d = 0; d < 64; ++d){ float xx = base[(size_t)d*1024]; s += xx*xx; }
    part[((size_t)(src*8 + y))*4096 + p] = s;
    return;
  }
  if (blk < 2336){                              // zero U+V (8192 floats)
    zUV[(blk - 2304)*256 + threadIdx.x] = 0.f;
    return;
  }
  zBNS[(blk - 2336)*256 + threadIdx.x] = 0.f;   // zero BN sums (1024 floats)
}

// NCHW fp32 -> points [p][d] bf16 hi/lo split (+aux); content & style in one launch
__global__ void tsplit_k(const float* __restrict__ cf, const float* __restrict__ sf,
                         const float* __restrict__ pnp,
                         u16* __restrict__ cfh, u16* __restrict__ cfl,
                         u16* __restrict__ sfh, u16* __restrict__ sfl,
                         u16* __restrict__ tcp, u16* __restrict__ snb){
  __shared__ float tile[64][65];
  int z = blockIdx.z, is_style = z >> 2, b = z & 3;
  const float* src = is_style ? sf : cf;
  u16* hi = is_style ? sfh : cfh;
  u16* lo = is_style ? sfl : cfl;
  int p0 = blockIdx.x*64, d0 = blockIdx.y*64;
  int r = threadIdx.x >> 2, c0 = (threadIdx.x & 3) * 16;
  const float* sp = src + ((size_t)(b*512 + d0 + r))*1024 + p0 + c0;
  float v[16];
  #pragma unroll
  for (int e = 0; e < 4; ++e){
    float4 t4 = ((const float4*)sp)[e];
    v[e*4+0]=t4.x; v[e*4+1]=t4.y; v[e*4+2]=t4.z; v[e*4+3]=t4.w;
  }
  #pragma unroll
  for (int j = 0; j < 16; ++j) tile[r][c0+j] = v[j];
  if (is_style){
    u16 t16[16];
    #pragma unroll
    for (int j = 0; j < 16; ++j) t16[j] = f2bf(v[j]);
    uint4* ap = (uint4*)(snb + ((size_t)(b*512 + d0 + r))*1024 + p0 + c0);
    ap[0] = pack8(t16); ap[1] = pack8(t16+8);
  }
  __syncthreads();
  int pr = r, dc0 = c0;
  float inv;
  {
    const float* pp = pnp + (size_t)(is_style ? 8*4096 : 0) + ((b<<10) + p0 + pr);
    float s = 0.f;
    #pragma unroll
    for (int j = 0; j < 8; ++j) s += pp[j*4096];
    inv = rsqrtf(s);
  }
  u16 h16[16], l16[16], t16[16];
  #pragma unroll
  for (int j = 0; j < 16; ++j){
    float x = tile[dc0+j][pr];
    t16[j] = f2bf(x);
    float xn = x * inv;
    u16 h = f2bf(xn);
    h16[j] = h;
    l16[j] = f2bf(xn - bf2f(h));
  }
  size_t orow = (size_t)((b<<10) + p0 + pr);
  uint4* hp = (uint4*)(hi + orow*512 + d0 + dc0);
  uint4* lp = (uint4*)(lo + orow*512 + d0 + dc0);
  hp[0] = pack8(h16); hp[1] = pack8(h16+8);
  lp[0] = pack8(l16); lp[1] = pack8(l16+8);
  if (!is_style){                              // content -> packed tc chunks 16..31
    int D = d0 + dc0;
    size_t off = ((size_t)(16 + (D>>5))*4096 + orow)*32 + (D&31);
    *(uint4*)(tcp + off)     = pack8(t16);
    *(uint4*)(tcp + off + 8) = pack8(t16+8);
  }
}

// ---------------- C-GEMM: G = (cfn.sfn - 1)*SCL, split bf16
// Direct staging; LDS-tiled epilogue writes BOTH G and Gt coalesced
// (fuses the former trans_k; R8 showed scattered 2-B stores cost 7.5x writes).
__global__ __launch_bounds__(256) void cgemm_k(const u16* __restrict__ cfh, const u16* __restrict__ cfl,
        const u16* __restrict__ sfh, const u16* __restrict__ sfl,
        u16* __restrict__ G, u16* __restrict__ Gt){
  __shared__ __align__(16) u16 SH[4*128*40];   // 40 KB staging; epilogue reuses (needs 34 KB)
  u16* Ah = SH;          u16* Al = SH + 5120;
  u16* Bh = SH + 10240;  u16* Bl = SH + 15360;
  int b = blockIdx.z;
  size_t abase = ((size_t)((b<<10) + blockIdx.x*128))*512;
  size_t bbase = ((size_t)((b<<10) + blockIdx.y*128))*512;
  int lane = threadIdx.x & 63, wid = threadIdx.x >> 6;
  int wm = (wid >> 1)*64, wn = (wid & 1)*64;
  int fr = lane & 15, qd = lane >> 4;
  int sr = threadIdx.x >> 1, sc = (threadIdx.x & 1)*16;
  f32x4 acc[4][4] = {};
  for (int kk = 0; kk < 512; kk += 32){
    size_t g0 = (size_t)sr*512 + kk + sc;
    *(uint4*)&Ah[sr*40+sc]   = *(const uint4*)(cfh + abase + g0);
    *(uint4*)&Ah[sr*40+sc+8] = *(const uint4*)(cfh + abase + g0 + 8);
    *(uint4*)&Al[sr*40+sc]   = *(const uint4*)(cfl + abase + g0);
    *(uint4*)&Al[sr*40+sc+8] = *(const uint4*)(cfl + abase + g0 + 8);
    *(uint4*)&Bh[sr*40+sc]   = *(const uint4*)(sfh + bbase + g0);
    *(uint4*)&Bh[sr*40+sc+8] = *(const uint4*)(sfh + bbase + g0 + 8);
    *(uint4*)&Bl[sr*40+sc]   = *(const uint4*)(sfl + bbase + g0);
    *(uint4*)&Bl[sr*40+sc+8] = *(const uint4*)(sfl + bbase + g0 + 8);
    __syncthreads();
    bf16x8 bhf[4], blf[4];
    #pragma unroll
    for (int ni = 0; ni < 4; ++ni){
      bhf[ni] = ldfrag(&Bh[(wn + ni*16 + fr)*40 + qd*8]);
      blf[ni] = ldfrag(&Bl[(wn + ni*16 + fr)*40 + qd*8]);
    }
    #pragma unroll
    for (int mi = 0; mi < 4; ++mi){
      bf16x8 ah = ldfrag(&Ah[(wm + mi*16 + fr)*40 + qd*8]);
      bf16x8 al = ldfrag(&Al[(wm + mi*16 + fr)*40 + qd*8]);
      #pragma unroll
      for (int ni = 0; ni < 4; ++ni){
        acc[mi][ni] = mfma16(ah, bhf[ni], acc[mi][ni]);
        acc[mi][ni] = mfma16(ah, blf[ni], acc[mi][ni]);
        acc[mi][ni] = mfma16(al, bhf[ni], acc[mi][ni]);
      }
    }
    __syncthreads();
  }
  // epilogue pass 1: C tile row-major in LDS -> coalesced G stores
  #pragma unroll
  for (int mi = 0; mi < 4; ++mi)
    #pragma unroll
    for (int ni = 0; ni < 4; ++ni)
      #pragma unroll
      for (int rg = 0; rg < 4; ++rg){
        int r = wm + mi*16 + qd*4 + rg;
        int c = wn + ni*16 + fr;
        SH[r*136 + c] = f2h((acc[mi][ni][rg] - 1.f) * SCL);
      }
  __syncthreads();
  size_t gb = (((size_t)b) << 20) + (size_t)(blockIdx.x*128)*1024 + blockIdx.y*128;
  #pragma unroll
  for (int i = 0; i < 8; ++i){
    int idx = i*256 + threadIdx.x;
    int r = idx >> 4, c4 = idx & 15;
    *(uint4*)(G + gb + (size_t)r*1024 + c4*8) = *(const uint4*)&SH[r*136 + c4*8];
  }
  // epilogue pass 2: transposed tile -> coalesced Gt stores
  __syncthreads();
  #pragma unroll
  for (int mi = 0; mi < 4; ++mi)
    #pragma unroll
    for (int ni = 0; ni < 4; ++ni)
      #pragma unroll
      for (int rg = 0; rg < 4; ++rg){
        int r = wm + mi*16 + qd*4 + rg;
        int c = wn + ni*16 + fr;
        SH[c*136 + r] = f2h((acc[mi][ni][rg] - 1.f) * SCL);
      }
  __syncthreads();
  size_t gtb = (((size_t)b) << 20) + (size_t)(blockIdx.y*128)*1024 + blockIdx.x*128;
  #pragma unroll
  for (int i = 0; i < 8; ++i){
    int idx = i*256 + threadIdx.x;
    int r = idx >> 4, c4 = idx & 15;
    *(uint4*)(Gt + gtb + (size_t)r*1024 + c4*8) = *(const uint4*)&SH[r*136 + c4*8];
  }
}

// ---------------- Sinkhorn log2-domain pass over f16 matrix
__global__ void lse_k(const u16* __restrict__ M, const float* __restrict__ addv,
                      float* __restrict__ outv){
  int row = blockIdx.x*4 + (threadIdx.x >> 6);
  int lane = threadIdx.x & 63;
  int b = row >> 10;
  const uint4* r4 = (const uint4*)(M + ((size_t)row << 10));
  const float4* a4 = (const float4*)(addv + ((size_t)b << 10));
  float x[16]; float mx = -3.0e38f;
  #pragma unroll
  for (int e = 0; e < 2; ++e){
    uint4 g = r4[lane + 64*e];
    float4 a0 = a4[2*(lane + 64*e)];
    float4 a1 = a4[2*(lane + 64*e) + 1];
    u32 w[4] = {g.x, g.y, g.z, g.w};
    float av[8] = {a0.x,a0.y,a0.z,a0.w,a1.x,a1.y,a1.z,a1.w};
    #pragma unroll
    for (int i = 0; i < 8; ++i){
      u16 hv = (u16)((i & 1) ? (w[i>>1] >> 16) : (w[i>>1] & 0xffffu));
      float t = h2f(hv) + av[i];
      x[e*8+i] = t;
      mx = fmaxf(mx, t);
    }
  }
  #pragma unroll
  for (int m = 32; m >= 1; m >>= 1) mx = fmaxf(mx, __shfl_xor(mx, m, 64));
  float s = 0.f;
  #pragma unroll
  for (int i = 0; i < 16; ++i) s += exp2f(x[i] - mx);
  #pragma unroll
  for (int m = 32; m >= 1; m >>= 1) s += __shfl_xor(s, m, 64);
  if (lane == 0) outv[row] = LOG2MU - (mx + log2f(s));
}

// ---------------- pi materialization: pip[row][j] = bf16(2^(G+U+V+10))
__global__ void pi_k(const u16* __restrict__ G, const float* __restrict__ U,
                     const float* __restrict__ V, u16* __restrict__ pip){
  int t = threadIdx.x;
  int row = blockIdx.x*2 + (t >> 7);
  int b = row >> 10;
  int j0 = (t & 127) * 8;
  float ur = U[row] + 10.f;                    // +10: fold pi * 1024
  uint4 g = *(const uint4*)(G + ((size_t)row << 10) + j0);
  const float4* v4 = (const float4*)(V + ((size_t)b << 10) + j0);
  float4 va = v4[0], vb = v4[1];
  u32 gw[4] = {g.x, g.y, g.z, g.w};
  float vv[8] = {va.x,va.y,va.z,va.w,vb.x,vb.y,vb.z,vb.w};
  u16 o[8];
  #pragma unroll
  for (int i = 0; i < 8; ++i){
    u16 hv = (u16)((i & 1) ? (gw[i>>1] >> 16) : (gw[i>>1] & 0xffffu));
    o[i] = f2bf(exp2f(h2f(hv) + vv[i] + ur));
  }
  *(uint4*)(pip + ((size_t)row << 10) + j0) = pack8(o);
}

// ---------------- t = pi @ sf: pure bf16 GEMM, 64p x 128d tiles, reg prefetch
__global__ __launch_bounds__(256) void tgemm_k(const u16* __restrict__ pip,
        const u16* __restrict__ snb, float* __restrict__ tn, u16* __restrict__ tcp){
  __shared__ __align__(16) u16 As[64*40], Bs[128*40];
  int b = blockIdx.z, p0 = blockIdx.x*64, d0 = blockIdx.y*128;
  int tid = threadIdx.x, lane = tid & 63, wid = tid >> 6;
  int wm = (wid >> 1)*32, wn = (wid & 1)*64;
  int fr = lane & 15, qd = lane >> 4;
  int a_r = tid >> 2, a_c = (tid & 3)*8;
  int b_r = tid >> 1, b_c = (tid & 1)*16;
  const u16* Arow = pip + (((size_t)((b<<10) + p0 + a_r)) << 10) + a_c;
  const u16* Brow = snb + (((size_t)(b*512 + d0 + b_r)) << 10) + b_c;
  uint4 pa, pb0, pb1;
  auto issue = [&](int kk){
    pa = *(const uint4*)(Arow + kk);
    const uint4* bp = (const uint4*)(Brow + kk);
    pb0 = bp[0]; pb1 = bp[1];
  };
  f32x4 acc[2][4] = {};
  issue(0);
  for (int kk = 0; kk < 1024; kk += 32){
    *(uint4*)&As[a_r*40 + a_c] = pa;
    *(uint4*)&Bs[b_r*40 + b_c] = pb0;
    *(uint4*)&Bs[b_r*40 + b_c + 8] = pb1;
    __syncthreads();
    if (kk + 32 < 1024) issue(kk + 32);
    bf16x8 bfr[4];
    #pragma unroll
    for (int ni = 0; ni < 4; ++ni) bfr[ni] = ldfrag(&Bs[(wn + ni*16 + fr)*40 + qd*8]);
    #pragma unroll
    for (int mi = 0; mi < 2; ++mi){
      bf16x8 afr = ldfrag(&As[(wm + mi*16 + fr)*40 + qd*8]);
      #pragma unroll
      for (int ni = 0; ni < 4; ++ni) acc[mi][ni] = mfma16(afr, bfr[ni], acc[mi][ni]);
    }
    __syncthreads();
  }
  #pragma unroll
  for (int mi = 0; mi < 2; ++mi)
    #pragma unroll
    for (int ni = 0; ni < 4; ++ni)
      #pragma unroll
      for (int rg = 0; rg < 4; ++rg){
        int p = p0 + wm + mi*16 + qd*4 + rg;
        int d = d0 + wn + ni*16 + fr;
        float vout = acc[mi][ni][rg];
        size_t ro = (size_t)((b<<10) + p);
        tn[ro*512 + d] = vout;
        tcp[((size_t)(d>>5)*4096 + ro)*32 + (d&31)] = f2bf(vout);
      }
}

// ---------------- implicit-GEMM 3x3 conv: packed activations, frag-order weights
template<int CI, int CO, int KSPLIT, int MODE>
__global__ __launch_bounds__(256) void conv_k(const u16* __restrict__ inp, const u16* __restrict__ wpk,
        const float* __restrict__ bias, float* __restrict__ fout, u16* __restrict__ bout,
        const u16* __restrict__ tcp, const float* __restrict__ cnm, const float* __restrict__ cnis,
        const float* __restrict__ tn){
  constexpr int NCK_TOT = CI/32, NCK = NCK_TOT/KSPLIT;
  __shared__ __align__(16) u16 As[128*40];
  int b = blockIdx.z & 3, ks = blockIdx.z >> 2;
  int c0 = blockIdx.y*64;
  int r0 = blockIdx.x*2;
  int tid = threadIdx.x, lane = tid & 63, wid = tid >> 6;
  int wm = (wid >> 1)*32, wn = (wid & 1)*32;
  int fr = lane & 15, qd = lane >> 4;
  int ck0 = ks*NCK;
  int hrow = tid >> 1;
  int ah = (tid & 1)*16;
  int gy = r0 - 1 + (hrow >> 5);
  bool a_ok = ((unsigned)gy < 32u);
  size_t arow = (size_t)(b<<10) + (r0-1)*32 + hrow;
  uint4 pa0 = {0,0,0,0}, pa1 = {0,0,0,0};
  auto issueA = [&](int ck){
    if (a_ok){
      const uint4* s = (const uint4*)(inp + ((size_t)(ck0+ck)*4096 + arow)*32 + ah);
      pa0 = s[0]; pa1 = s[1];
    }
  };
  int g0 = (c0 + wn) >> 4;
  const u16* wb0 = wpk + ((size_t)(g0    )*NCK_TOT + ck0)*9*512 + lane*8;
  const u16* wb1 = wpk + ((size_t)(g0 + 1)*NCK_TOT + ck0)*9*512 + lane*8;

  f32x4 acc[2][2] = {};
  issueA(0);
  for (int ck = 0; ck < NCK; ++ck){
    *(uint4*)&As[hrow*40 + ah]     = pa0;
    *(uint4*)&As[hrow*40 + ah + 8] = pa1;
    __syncthreads();
    if (ck + 1 < NCK) issueA(ck + 1);
    #pragma unroll
    for (int tap = 0; tap < 9; ++tap){
      const int dy = tap/3 - 1, dx = tap%3 - 1;
      bf16x8 bf0 = ldfrag(wb0 + (size_t)(ck*9 + tap)*512);
      bf16x8 bf1 = ldfrag(wb1 + (size_t)(ck*9 + tap)*512);
      #pragma unroll
      for (int mi = 0; mi < 2; ++mi){
        int p0w = wm + mi*16;
        int pcol = (p0w & 31) + fr + dx;
        int lr = (p0w >> 5) + dy + 1;
        bool okc = (unsigned)pcol < 32u;
        bf16x8 af = ldfrag(&As[(lr*32 + (okc ? pcol : 0))*40 + qd*8]);
        if (!okc) af = bf16x8(0);
        acc[mi][0] = mfma16(af, bf0, acc[mi][0]);
        acc[mi][1] = mfma16(af, bf1, acc[mi][1]);
      }
    }
    __syncthreads();
  }
  #pragma unroll
  for (int mi = 0; mi < 2; ++mi)
    #pragma unroll
    for (int ni = 0; ni < 2; ++ni)
      #pragma unroll
      for (int rg = 0; rg < 4; ++rg){
        int pp = blockIdx.x*64 + wm + mi*16 + qd*4 + rg;
        int cc = c0 + wn + ni*16 + fr;
        float v = acc[mi][ni][rg];
        size_t ro = (size_t)((b<<10) + pp);
        if (MODE == 0){
          fout[(size_t)ks*4096*CO + ro*CO + cc] = v;
        } else {
          float alpha = v + bias[cc];
          float cn = (bf2f(tcp[((size_t)(16 + (cc>>5))*4096 + ro)*32 + (cc&31)])
                      - cnm[(b<<9) + cc]) * cnis[(b<<9) + cc];
          bout[((size_t)(cc>>5)*4096 + ro)*32 + (cc&31)] = f2bf(alpha*cn + tn[ro*512 + cc]);
        }
      }
}

// ---------------- decoder conv (512 -> 3): VALU reduction over packed t2
// 128 blocks x 512 thr (32 px/block): halves per-block weight-staging redundancy
__global__ __launch_bounds__(512) void dec_k(const u16* __restrict__ t2p, const u16* __restrict__ wdp,
                                             const float* __restrict__ db, float* __restrict__ out){
  __shared__ float wlds[3*4608];
  int tid = threadIdx.x;
  for (int k = tid; k < 3*4608; k += 512){
    int c = k / 4608, rem = k - c*4608;
    int tap = rem >> 9, ci = rem & 511;
    wlds[k] = bf2f(wdp[(size_t)(tap*16 + c)*512 + ci]);
  }
  __syncthreads();
  int b = blockIdx.x >> 5;
  int p = ((blockIdx.x & 31) << 5) + (tid >> 4);
  int sub = tid & 15;
  int py = p >> 5, px = p & 31;
  float a0 = 0.f, a1 = 0.f, a2 = 0.f;
  for (int tap = 0; tap < 9; ++tap){
    int sy = py + tap/3 - 1, sx = px + tap%3 - 1;
    if (((unsigned)sy < 32u) && ((unsigned)sx < 32u)){
      size_t row = (size_t)((b<<10) + (sy<<5) + sx);
      const float* w0 = wlds + tap*512;
      #pragma unroll
      for (int j = 0; j < 4; ++j){
        int ci0 = j*128 + sub*8;
        uint4 v = *(const uint4*)(t2p + ((size_t)(ci0>>5)*4096 + row)*32 + (ci0&31));
        u32 ww[4] = {v.x, v.y, v.z, v.w};
        #pragma unroll
        for (int e = 0; e < 8; ++e){
          float x = bf2f((u16)((e & 1) ? (ww[e>>1] >> 16) : (ww[e>>1] & 0xffffu)));
          a0 += x * w0[ci0 + e];
          a1 += x * w0[4608 + ci0 + e];
          a2 += x * w0[9216 + ci0 + e];
        }
      }
    }
  }
  #pragma unroll
  for (int m = 8; m >= 1; m >>= 1){
    a0 += __shfl_xor(a0, m, 64);
    a1 += __shfl_xor(a1, m, 64);
    a2 += __shfl_xor(a2, m, 64);
  }
  if (sub == 0){
    out[((size_t)(b*3 + 0) << 10) + p] = a0 + db[0];
    out[((size_t)(b*3 + 1) << 10) + p] = a1 + db[1];
    out[((size_t)(b*3 + 2) << 10) + p] = a2 + db[2];
  }
}

// ---------------- BN over K-split partials: x = relu(za+zb+bias) ----------------
__global__ void bn_stats_k(const float* __restrict__ z, const float* __restrict__ bias,
                           float* __restrict__ sums){
  int c = blockIdx.x*64 + (threadIdx.x & 63);
  int w = threadIdx.x >> 6;
  int rbase = blockIdx.y*512 + w*128;
  float bi = bias[c];
  float s = 0.f, q = 0.f;
  for (int i = 0; i < 128; ++i){
    size_t ro = (size_t)(rbase + i)*256 + c;
    float x = fmaxf(z[ro] + z[4096*256 + ro] + bi, 0.f);
    s += x; q += x*x;
  }
  __shared__ float ls[4][64], lq[4][64];
  ls[w][threadIdx.x & 63] = s; lq[w][threadIdx.x & 63] = q;
  __syncthreads();
  if (threadIdx.x < 64){
    float S = ls[0][threadIdx.x]+ls[1][threadIdx.x]+ls[2][threadIdx.x]+ls[3][threadIdx.x];
    float Q = lq[0][threadIdx.x]+lq[1][threadIdx.x]+lq[2][threadIdx.x]+lq[3][threadIdx.x];
    atomicAdd(&sums[blockIdx.x*64 + threadIdx.x], S);
    atomicAdd(&sums[256 + blockIdx.x*64 + threadIdx.x], Q);
  }
}

// bn_apply with inline finalize
__global__ void bn_apply_k(const float* __restrict__ z, const float* __restrict__ bias,
                           const float* __restrict__ sums, const float* __restrict__ gamma,
                           const float* __restrict__ beta, u16* __restrict__ ap){
  int idx = blockIdx.x*256 + threadIdx.x;
  float4 va = ((const float4*)z)[idx];
  float4 vb = ((const float4*)(z + 4096*256))[idx];
  int row = idx >> 6;
  int cc0 = (idx << 2) & 255;
  float e[4] = {va.x+vb.x, va.y+vb.y, va.z+vb.z, va.w+vb.w};
  u16 o[4];
  #pragma unroll
  for (int k = 0; k < 4; ++k){
    int c = cc0 + k;
    float mean = sums[c] * (1.f/4096.f);
    float var  = sums[256 + c] * (1.f/4096.f) - mean*mean;
    float sc = gamma[c] * rsqrtf(var + 1e-5f);
    float sh = beta[c] - mean*sc;
    float x = fmaxf(e[k] + bias[c], 0.f);
    o[k] = f2bf(x*sc + sh);
  }
  uint2 pk; pk.x = (u32)o[0] | ((u32)o[1]<<16); pk.y = (u32)o[2] | ((u32)o[3]<<16);
  *(uint2*)(ap + ((size_t)(cc0>>5)*4096 + row)*32 + (cc0&31)) = pk;
}

// ---------------- launch ----------------
extern "C" void kernel_launch(void* const* d_in, const int* in_sizes, int n_in,
                              void* d_out, int out_size, void* d_ws, size_t ws_size,
                              hipStream_t stream){
  const float* cf  = (const float*)d_in[0];
  const float* sf  = (const float*)d_in[1];
  const float* w1  = (const float*)d_in[2];
  const float* b1  = (const float*)d_in[3];
  const float* g1  = (const float*)d_in[4];
  const float* be1 = (const float*)d_in[5];
  const float* w2  = (const float*)d_in[6];
  const float* b2  = (const float*)d_in[7];
  const float* g2  = (const float*)d_in[8];
  const float* be2 = (const float*)d_in[9];
  const float* w3  = (const float*)d_in[10];
  const float* b3  = (const float*)d_in[11];
  const float* dw  = (const float*)d_in[12];
  const float* db  = (const float*)d_in[13];

  char* ws = (char*)d_ws;
  u16* G    = (u16*)(ws + OFF_G);
  u16* Gt   = (u16*)(ws + OFF_GT);
  float* U    = (float*)(ws + OFF_U);
  float* V    = (float*)(ws + OFF_V);
  float* cnm  = (float*)(ws + OFF_CNM);
  float* cnis = (float*)(ws + OFF_CNIS);
  float* bns1 = (float*)(ws + OFF_BNS);
  float* bns2 = bns1 + 512;
  float* pnp  = (float*)(ws + OFF_PNP);
  u16* cfh = (u16*)(ws + OFF_CFH);
  u16* cfl = (u16*)(ws + OFF_CFL);
  u16* sfh = (u16*)(ws + OFF_SFH);
  u16* sfl = (u16*)(ws + OFF_SFL);
  u16* snb = (u16*)(ws + OFF_SNB);
  float* tn  = (float*)(ws + OFF_TN);
  u16* tcp = (u16*)(ws + OFF_TCP);
  u16* w1p = (u16*)(ws + OFF_W1P);
  u16* w2p = (u16*)(ws + OFF_W2P);
  u16* w3p = (u16*)(ws + OFF_W3P);
  u16* wdp = (u16*)(ws + OFF_WDP);
  u16* pip = (u16*)(ws + OFF_PIP);
  float* z1  = (float*)(ws + OFF_Z1);
  u16*   a1p = (u16*)(ws + OFF_A1P);
  float* z2  = (float*)(ws + OFF_Z2);
  u16*   a2p = (u16*)(ws + OFF_A2P);
  u16*   t2p = (u16*)(ws + OFF_T2P);

  pack_all_k<<<1184, 256, 0, stream>>>(w1, w2, w3, dw, w1p, w2p, w3p, wdp);

  stats_k<<<2340, 256, 0, stream>>>(cf, sf, cnm, cnis, pnp, U, bns1);
  tsplit_k<<<dim3(16, 8, 8), 256, 0, stream>>>(cf, sf, pnp, cfh, cfl, sfh, sfl, tcp, snb);

  cgemm_k<<<dim3(8, 8, 4), 256, 0, stream>>>(cfh, cfl, sfh, sfl, G, Gt);

  for (int it = 0; it < 20; ++it){
    lse_k<<<1024, 256, 0, stream>>>(G,  V, U);
    lse_k<<<1024, 256, 0, stream>>>(Gt, U, V);
  }

  pi_k<<<2048, 256, 0, stream>>>(G, U, V, pip);
  tgemm_k<<<dim3(16, 4, 4), 256, 0, stream>>>(pip, snb, tn, tcp);

  conv_k<1024, 256, 2, 0><<<dim3(16, 4, 8), 256, 0, stream>>>(
      tcp, w1p, nullptr, z1, nullptr, nullptr, nullptr, nullptr, nullptr);
  bn_stats_k<<<dim3(4, 8), 256, 0, stream>>>(z1, b1, bns1);
  bn_apply_k<<<1024, 256, 0, stream>>>(z1, b1, bns1, g1, be1, a1p);

  conv_k<256, 256, 2, 0><<<dim3(16, 4, 8), 256, 0, stream>>>(
      a1p, w2p, nullptr, z2, nullptr, nullptr, nullptr, nullptr, nullptr);
  bn_stats_k<<<dim3(4, 8), 256, 0, stream>>>(z2, b2, bns2);
  bn_apply_k<<<1024, 256, 0, stream>>>(z2, b2, bns2, g2, be2, a2p);

  conv_k<256, 512, 1, 1><<<dim3(16, 8, 4), 256, 0, stream>>>(
      a2p, w3p, b3, nullptr, t2p, tcp, cnm, cnis, tn);

  dec_k<<<128, 512, 0, stream>>>(t2p, wdp, db, (float*)d_out);

  (void)in_sizes; (void)n_in; (void)out_size; (void)ws_size;
}